// Round 1
// baseline (359697.461 us; speedup 1.0000x reference)
//
#include <hip/hip_runtime.h>
#include <math.h>

// ---------------------------------------------------------------------------
// GOTSim: GCN features -> GED cost matrices -> exact JV LAP -> score
// N1=N2=384, E=3072, layers 32->128->64->32, LAP size 768.
// ---------------------------------------------------------------------------

namespace {
constexpr int kN   = 384;   // nodes per graph
constexpr int kNN  = 768;   // LAP dimension
constexpr int kE   = 3072;  // edges per graph
constexpr float kBig = 99999.0f;
constexpr float kInf = 1e30f;
}

// ---- degree / dinv --------------------------------------------------------

__global__ void init_deg(float* deg1, float* deg2) {
    int v = blockIdx.x * blockDim.x + threadIdx.x;
    if (v < kN) { deg1[v] = 1.0f; deg2[v] = 1.0f; }  // self-loop counts 1
}

__global__ void scatter_deg(const int* ei1, const int* ei2, float* deg1, float* deg2) {
    int e = blockIdx.x * blockDim.x + threadIdx.x;
    if (e < kE) {
        atomicAdd(&deg1[ei1[kE + e]], 1.0f);          // dst of graph 1
    } else if (e < 2 * kE) {
        atomicAdd(&deg2[ei2[kE + (e - kE)]], 1.0f);   // dst of graph 2
    }
}

__global__ void deg_to_dinv(float* deg1, float* deg2) {
    int v = blockIdx.x * blockDim.x + threadIdx.x;
    if (v < kN) { deg1[v] = rsqrtf(deg1[v]); deg2[v] = rsqrtf(deg2[v]); }
}

// ---- GCN layer ------------------------------------------------------------

// h[row, oc] = sum_k act(x[row, k]) * w[k, oc]
__global__ void gemm_act(const float* __restrict__ x, const float* __restrict__ w,
                         float* __restrict__ h, int FIN, int FOUT, int relu) {
    int idx = blockIdx.x * blockDim.x + threadIdx.x;
    if (idx >= kN * FOUT) return;
    int row = idx / FOUT;
    int oc  = idx - row * FOUT;
    float acc = 0.0f;
    for (int k = 0; k < FIN; ++k) {
        float xv = x[row * FIN + k];
        if (relu) xv = fmaxf(xv, 0.0f);
        acc += xv * w[k * FOUT + oc];
    }
    h[idx] = acc;
}

// out[v, f] = b[f] + dinv[v]^2 * h[v, f]   (self loop + bias)
__global__ void agg_init(const float* __restrict__ h, const float* __restrict__ dinv,
                         const float* __restrict__ b, float* __restrict__ out, int F) {
    int idx = blockIdx.x * blockDim.x + threadIdx.x;
    if (idx >= kN * F) return;
    int v = idx / F;
    int f = idx - v * F;
    float dv = dinv[v];
    out[idx] = b[f] + dv * dv * h[idx];
}

// out[dst, f] += dinv[src]*dinv[dst]*h[src, f]
__global__ void agg_edges(const int* __restrict__ ei, const float* __restrict__ h,
                          const float* __restrict__ dinv, float* __restrict__ out, int F) {
    int idx = blockIdx.x * blockDim.x + threadIdx.x;
    if (idx >= kE * F) return;
    int e = idx / F;
    int f = idx - e * F;
    int s = ei[e];
    int d = ei[kE + e];
    atomicAdd(&out[d * F + f], dinv[s] * dinv[d] * h[s * F + f]);
}

// ---- cost matrix ----------------------------------------------------------

__global__ void build_cost(float* __restrict__ C, const float* __restrict__ f1,
                           const float* __restrict__ f2, const float* __restrict__ delp,
                           const float* __restrict__ insp, int F) {
    int j = blockIdx.x * blockDim.x + threadIdx.x;
    int i = blockIdx.y;
    if (j >= kNN) return;
    float val;
    if (i < kN && j < kN) {
        float acc = 0.0f;
        for (int k = 0; k < F; ++k) acc += f1[i * F + k] * f2[j * F + k];
        val = -acc;
    } else if (i < kN) {                 // top-right: del_sim (diag) + BIG off-diag
        int k2 = j - kN;
        if (k2 == i) {
            float acc = 0.0f;
            for (int k = 0; k < F; ++k) acc += f1[i * F + k] * delp[k];
            val = -acc;
        } else val = kBig;
    } else if (j < kN) {                 // bottom-left: ins_sim (diag) + BIG off-diag
        int i2 = i - kN;
        if (i2 == j) {
            float acc = 0.0f;
            for (int k = 0; k < F; ++k) acc += f2[i2 * F + k] * insp[k];
            val = -acc;
        } else val = kBig;
    } else {
        val = 0.0f;                      // bottom-right dummy
    }
    C[i * kNN + j] = val;
}

// ---- LAP (Jonker-Volgenant shortest augmenting path), one wave per matrix -

__global__ __launch_bounds__(64) void lap_kernel(const float* __restrict__ Call,
                                                 float* __restrict__ loss_out) {
    const int m = blockIdx.x;
    const float* C = Call + (size_t)m * kNN * kNN;

    __shared__ float u[kNN], v[kNN], sh_short[kNN];
    __shared__ int row4col[kNN], col4row[kNN], pathj[kNN];
    __shared__ int srlist[kNN], sclist[kNN];

    const int lane = threadIdx.x;

    for (int j = lane; j < kNN; j += 64) {
        u[j] = 0.0f; v[j] = 0.0f; row4col[j] = -1; col4row[j] = -1;
    }
    __syncthreads();

    for (int cur = 0; cur < kNN; ++cur) {
        // per-row lane-private state: 12 columns per lane (lane + 64*k)
        float sreg[12], vreg[12];
        bool  screg[12];
        #pragma unroll
        for (int k = 0; k < 12; ++k) {
            sreg[k]  = kInf;
            vreg[k]  = v[lane + 64 * k];
            screg[k] = false;
        }

        float min_val = 0.0f;
        int   i    = cur;
        int   sink = -1;
        int   nstep = 0;

        while (sink < 0) {
            if (lane == 0) srlist[nstep] = i;
            float base = min_val - u[i];
            const float* Crow = C + (size_t)i * kNN;

            float best = kInf;
            int   bj   = 0;
            #pragma unroll
            for (int k = 0; k < 12; ++k) {
                int j = lane + 64 * k;
                float c = Crow[j];          // unconditional -> loads pipeline
                if (!screg[k]) {
                    float d = base + c - vreg[k];
                    if (d < sreg[k]) {
                        sreg[k] = d;
                        sh_short[j] = d;    // mirror for epilogue cross-lane reads
                        pathj[j] = i;
                    }
                    if (sreg[k] < best) { best = sreg[k]; bj = j; }
                }
            }
            // wave argmin (64 lanes)
            #pragma unroll
            for (int off = 32; off > 0; off >>= 1) {
                float ob = __shfl_down(best, off);
                int   oj = __shfl_down(bj, off);
                if (ob < best) { best = ob; bj = oj; }
            }
            best = __shfl(best, 0);
            bj   = __shfl(bj, 0);
            min_val = best;

            if (lane == (bj & 63)) screg[bj >> 6] = true;
            if (lane == 0) sclist[nstep] = bj;
            ++nstep;

            int r4 = row4col[bj];
            if (r4 < 0) sink = bj; else i = r4;
        }

        __syncthreads();  // make sh_short/pathj/srlist/sclist visible block-wide

        // dual updates over visited rows/cols only (lists are short)
        for (int t = lane; t < nstep; t += 64) {
            int r = srlist[t];
            if (r != cur) u[r] += min_val - sh_short[col4row[r]];
            int jc = sclist[t];
            v[jc] -= min_val - sh_short[jc];
        }
        if (lane == 0) {
            u[cur] += min_val;
            // augment along path
            int j = sink;
            for (;;) {
                int ii = pathj[j];
                row4col[j] = ii;
                int nxt = col4row[ii];
                col4row[ii] = j;
                j = nxt;
                if (ii == cur) break;
            }
        }
        __syncthreads();
    }

    // loss = sum_i C[i, col4row[i]]
    float s = 0.0f;
    for (int r = lane; r < kNN; r += 64) {
        s += C[(size_t)r * kNN + col4row[r]];
    }
    #pragma unroll
    for (int off = 32; off > 0; off >>= 1) s += __shfl_down(s, off);
    if (lane == 0) loss_out[m] = s;
}

// ---- finalize -------------------------------------------------------------

__global__ void finalize(const float* __restrict__ loss_sums,
                         const float* __restrict__ score_w,
                         const float* __restrict__ score_b,
                         const float* __restrict__ avg_v,
                         float* __restrict__ out) {
    float mc[3];
    for (int m = 0; m < 3; ++m) mc[m] = 2.0f * (loss_sums[m] / (float)kNN) / (float)kNN;
    float logits = score_b[0];
    for (int m = 0; m < 3; ++m) logits += score_w[m] * mc[m];
    float score = 1.0f / (1.0f + expf(-logits));
    out[0] = score;
    out[1] = -logf(score) * avg_v[0];
    out[2] = mc[0];
    out[3] = mc[1];
    out[4] = mc[2];
}

// ---------------------------------------------------------------------------

extern "C" void kernel_launch(void* const* d_in, const int* in_sizes, int n_in,
                              void* d_out, int out_size, void* d_ws, size_t ws_size,
                              hipStream_t stream) {
    const int*   ei1 = (const int*)d_in[0];
    const int*   ei2 = (const int*)d_in[1];
    const float* x1  = (const float*)d_in[2];
    const float* x2  = (const float*)d_in[3];
    const float* avg = (const float*)d_in[6];

    // Input layout: setup_inputs() dict order vs reference signature order.
    // dict order:   7:w1 8:b1 9:del1 10:ins1 11:w2(8192) 12:b2 13:del2 14:ins2
    //               15:w3 16:b3 17:del3 18:ins3 19:sw 20:sb
    // sig  order:   7:w1 8:b1 9:w2(8192) 10:b2 11:w3(2048) 12:b3 13:del1.. 16:ins1..
    const float *w[3], *b[3], *dl[3], *insp[3], *score_w, *score_b;
    if (in_sizes[11] == 8192) {  // dict order
        w[0]=(const float*)d_in[7];  b[0]=(const float*)d_in[8];
        dl[0]=(const float*)d_in[9]; insp[0]=(const float*)d_in[10];
        w[1]=(const float*)d_in[11]; b[1]=(const float*)d_in[12];
        dl[1]=(const float*)d_in[13]; insp[1]=(const float*)d_in[14];
        w[2]=(const float*)d_in[15]; b[2]=(const float*)d_in[16];
        dl[2]=(const float*)d_in[17]; insp[2]=(const float*)d_in[18];
        score_w=(const float*)d_in[19]; score_b=(const float*)d_in[20];
    } else {                     // signature order
        w[0]=(const float*)d_in[7];  b[0]=(const float*)d_in[8];
        w[1]=(const float*)d_in[9];  b[1]=(const float*)d_in[10];
        w[2]=(const float*)d_in[11]; b[2]=(const float*)d_in[12];
        dl[0]=(const float*)d_in[13]; dl[1]=(const float*)d_in[14]; dl[2]=(const float*)d_in[15];
        insp[0]=(const float*)d_in[16]; insp[1]=(const float*)d_in[17]; insp[2]=(const float*)d_in[18];
        score_w=(const float*)d_in[19]; score_b=(const float*)d_in[20];
    }

    // Workspace layout (floats). Total ~7.6 MiB.
    float* ws = (float*)d_ws;
    float* f1[3] = { ws + 0,      ws + 49152,  ws + 73728  };  // 384x128,384x64,384x32
    float* f2[3] = { ws + 86016,  ws + 135168, ws + 159744 };
    float* h     = ws + 172032;                                 // 384x128 temp
    float* dinv1 = ws + 221184;                                 // 384
    float* dinv2 = ws + 221568;                                 // 384
    float* C     = ws + 221952;                                 // 3 x 768 x 768
    float* loss  = ws + 1991424;                                // 3

    // degrees -> dinv
    init_deg<<<6, 64, 0, stream>>>(dinv1, dinv2);
    scatter_deg<<<24, 256, 0, stream>>>(ei1, ei2, dinv1, dinv2);
    deg_to_dinv<<<6, 64, 0, stream>>>(dinv1, dinv2);

    const int Fs[3] = {128, 64, 32};
    for (int g = 0; g < 2; ++g) {
        const float* xin  = g ? x2  : x1;
        const int*   ei   = g ? ei2 : ei1;
        float*       dinv = g ? dinv2 : dinv1;
        float* const* f   = g ? f2 : f1;
        int fin = 32, relu = 0;
        for (int li = 0; li < 3; ++li) {
            int OF = Fs[li];
            int nthr = kN * OF;
            gemm_act<<<(nthr + 255) / 256, 256, 0, stream>>>(xin, w[li], h, fin, OF, relu);
            agg_init<<<(nthr + 255) / 256, 256, 0, stream>>>(h, dinv, b[li], f[li], OF);
            agg_edges<<<(kE * OF + 255) / 256, 256, 0, stream>>>(ei, h, dinv, f[li], OF);
            xin = f[li]; fin = OF; relu = 1;
        }
    }

    for (int m = 0; m < 3; ++m) {
        build_cost<<<dim3(3, kNN), 256, 0, stream>>>(C + (size_t)m * kNN * kNN,
                                                     f1[m], f2[m], dl[m], insp[m], Fs[m]);
    }

    lap_kernel<<<3, 64, 0, stream>>>(C, loss);
    finalize<<<1, 1, 0, stream>>>(loss, score_w, score_b, avg, (float*)d_out);
}

// Round 2
// 69325.146 us; speedup vs baseline: 5.1886x; 5.1886x over previous
//
#include <hip/hip_runtime.h>
#include <math.h>

// ---------------------------------------------------------------------------
// GOTSim: GCN features -> reduced 384x384 LAP (exact JV w/ dual init) -> score
// Structural identity: LAP_768(block matrix) = Sum(D)+Sum(I) +
//   LAP_384(min(0, M_ij - D_i - I_j)), since BIG entries are never optimal and
//   unmatched col j must pair with dummy row 384+j (diag-only ins block).
// ---------------------------------------------------------------------------

namespace {
constexpr int kN   = 384;   // nodes per graph == reduced LAP dimension
constexpr int kNN  = 768;   // original LAP dimension (for normalization)
constexpr int kE   = 3072;  // edges per graph
constexpr float kInf = 1e30f;
}

// ---- degree / dinv --------------------------------------------------------

__global__ void init_deg(float* deg1, float* deg2) {
    int v = blockIdx.x * blockDim.x + threadIdx.x;
    if (v < kN) { deg1[v] = 1.0f; deg2[v] = 1.0f; }  // self-loop counts 1
}

__global__ void scatter_deg(const int* ei1, const int* ei2, float* deg1, float* deg2) {
    int e = blockIdx.x * blockDim.x + threadIdx.x;
    if (e < kE) {
        atomicAdd(&deg1[ei1[kE + e]], 1.0f);
    } else if (e < 2 * kE) {
        atomicAdd(&deg2[ei2[kE + (e - kE)]], 1.0f);
    }
}

__global__ void deg_to_dinv(float* deg1, float* deg2) {
    int v = blockIdx.x * blockDim.x + threadIdx.x;
    if (v < kN) { deg1[v] = rsqrtf(deg1[v]); deg2[v] = rsqrtf(deg2[v]); }
}

// ---- GCN layer ------------------------------------------------------------

__global__ void gemm_act(const float* __restrict__ x, const float* __restrict__ w,
                         float* __restrict__ h, int FIN, int FOUT, int relu) {
    int idx = blockIdx.x * blockDim.x + threadIdx.x;
    if (idx >= kN * FOUT) return;
    int row = idx / FOUT;
    int oc  = idx - row * FOUT;
    float acc = 0.0f;
    for (int k = 0; k < FIN; ++k) {
        float xv = x[row * FIN + k];
        if (relu) xv = fmaxf(xv, 0.0f);
        acc += xv * w[k * FOUT + oc];
    }
    h[idx] = acc;
}

__global__ void agg_init(const float* __restrict__ h, const float* __restrict__ dinv,
                         const float* __restrict__ b, float* __restrict__ out, int F) {
    int idx = blockIdx.x * blockDim.x + threadIdx.x;
    if (idx >= kN * F) return;
    int v = idx / F;
    int f = idx - v * F;
    float dv = dinv[v];
    out[idx] = b[f] + dv * dv * h[idx];
}

__global__ void agg_edges(const int* __restrict__ ei, const float* __restrict__ h,
                          const float* __restrict__ dinv, float* __restrict__ out, int F) {
    int idx = blockIdx.x * blockDim.x + threadIdx.x;
    if (idx >= kE * F) return;
    int e = idx / F;
    int f = idx - e * F;
    int s = ei[e];
    int d = ei[kE + e];
    atomicAdd(&out[d * F + f], dinv[s] * dinv[d] * h[s * F + f]);
}

// ---- diag terms: D_i = -f1_i . del ; I_j = -f2_j . ins --------------------

__global__ void node_dots(const float* __restrict__ f, const float* __restrict__ p,
                          float* __restrict__ out, int F) {
    int i = blockIdx.x * blockDim.x + threadIdx.x;
    if (i >= kN) return;
    float acc = 0.0f;
    for (int k = 0; k < F; ++k) acc += f[i * F + k] * p[k];
    out[i] = -acc;
}

// ---- reduced cost matrix + column minima (order-preserving uint trick) ----
// All entries are <= 0.0f, so for bits b = __float_as_uint(c), larger uint
// == smaller (more negative) float. atomicMax(vbits) => float column min.

__global__ void build_cost_red(const float* __restrict__ f1, const float* __restrict__ f2,
                               const float* __restrict__ D, const float* __restrict__ I,
                               float* __restrict__ C, unsigned* __restrict__ vbits, int F) {
    int j = blockIdx.x * blockDim.x + threadIdx.x;
    int i = blockIdx.y;
    if (j >= kN) return;
    float acc = 0.0f;
    for (int k = 0; k < F; ++k) acc += f1[i * F + k] * f2[j * F + k];
    float val = (-acc) - D[i] - I[j];
    float c = fminf(0.0f, val);
    C[i * kN + j] = c;
    atomicMax(&vbits[j], __float_as_uint(c));
}

// ---- 384x384 exact JV LAP, one wave per matrix ----------------------------

__global__ __launch_bounds__(64) void lap384(const float* __restrict__ Call,
                                             const unsigned* __restrict__ vbits_all,
                                             const float* __restrict__ Dall,
                                             const float* __restrict__ Iall,
                                             float* __restrict__ loss_out) {
    const int m = blockIdx.x;
    const float* C = Call + (size_t)m * kN * kN;
    const unsigned* vb = vbits_all + m * kN;

    __shared__ float u[kN], v[kN], shrt[kN];
    __shared__ int x[kN], y[kN], pathj[kN], srl[kN], scl[kN];
    __shared__ int freelist[kN];
    __shared__ int nfree_sh;

    const int lane = threadIdx.x;

    // v_j from column minima; clear assignment
    for (int j = lane; j < kN; j += 64) {
        v[j] = __uint_as_float(vb[j]);
        x[j] = -1; y[j] = -1;
    }
    if (lane == 0) nfree_sh = 0;
    __syncthreads();

    // u_i = min_j (C_ij - v_j)   (6 rows per lane, gather across lanes)
    float umin[6];
    #pragma unroll
    for (int r = 0; r < 6; ++r) umin[r] = kInf;
    for (int j = 0; j < kN; ++j) {
        float vj = v[j];
        #pragma unroll
        for (int r = 0; r < 6; ++r)
            umin[r] = fminf(umin[r], C[(size_t)(lane + 64 * r) * kN + j] - vj);
    }
    #pragma unroll
    for (int r = 0; r < 6; ++r) u[lane + 64 * r] = umin[r];
    __syncthreads();

    // Greedy: assign each row to a tight free column (bitwise-exact equality,
    // since u_i is the fmin over the identical expression C_ij - v_j).
    for (int i = 0; i < kN; ++i) {
        float ui = u[i];
        const float* Crow = C + (size_t)i * kN;
        int cand = 1 << 30;
        #pragma unroll
        for (int r = 0; r < 6; ++r) {
            int j = lane + 64 * r;
            if (y[j] < 0 && (Crow[j] - v[j]) == ui && j < cand) cand = j;
        }
        #pragma unroll
        for (int off = 32; off > 0; off >>= 1)
            cand = min(cand, __shfl_down(cand, off));
        cand = __shfl(cand, 0);
        if (lane == 0) {
            if (cand < (1 << 30)) { x[i] = cand; y[cand] = i; }
            else freelist[nfree_sh++] = i;
        }
        __syncthreads();
    }

    const int nfree = nfree_sh;

    // Shortest augmenting path for each remaining free row
    for (int fi = 0; fi < nfree; ++fi) {
        const int cur = freelist[fi];
        float sreg[6], vreg[6];
        bool  screg[6];
        #pragma unroll
        for (int r = 0; r < 6; ++r) {
            sreg[r]  = kInf;
            vreg[r]  = v[lane + 64 * r];
            screg[r] = false;
        }

        float min_val = 0.0f;
        int   i    = cur;
        int   sink = -1;
        int   nstep = 0;

        while (sink < 0) {
            if (lane == 0) srl[nstep] = i;
            float base = min_val - u[i];
            const float* Crow = C + (size_t)i * kN;

            float best = kInf;
            int   bj   = 0;
            #pragma unroll
            for (int r = 0; r < 6; ++r) {
                int j = lane + 64 * r;
                float c = Crow[j];
                if (!screg[r]) {
                    float d = base + c - vreg[r];
                    if (d < sreg[r]) {
                        sreg[r] = d;
                        shrt[j] = d;
                        pathj[j] = i;
                    }
                    if (sreg[r] < best) { best = sreg[r]; bj = j; }
                }
            }
            #pragma unroll
            for (int off = 32; off > 0; off >>= 1) {
                float ob = __shfl_down(best, off);
                int   oj = __shfl_down(bj, off);
                if (ob < best) { best = ob; bj = oj; }
            }
            best = __shfl(best, 0);
            bj   = __shfl(bj, 0);
            min_val = best;

            if (lane == (bj & 63)) screg[bj >> 6] = true;
            if (lane == 0) scl[nstep] = bj;
            ++nstep;

            int r4 = y[bj];
            if (r4 < 0) sink = bj; else i = r4;
        }

        __syncthreads();  // publish shrt/pathj/srl/scl

        for (int t = lane; t < nstep; t += 64) {
            int r = srl[t];
            if (r != cur) u[r] += min_val - shrt[x[r]];
            int jc = scl[t];
            v[jc] -= min_val - shrt[jc];
        }
        if (lane == 0) {
            u[cur] += min_val;
            int j = sink;
            for (;;) {
                int ii = pathj[j];
                y[j] = ii;
                int nxt = x[ii];
                x[ii] = j;
                j = nxt;
                if (ii == cur) break;
            }
        }
        __syncthreads();
    }

    // loss = Sum_i D_i + Sum_j I_j + Sum_i C[i, x[i]]
    float s = 0.0f;
    for (int t = lane; t < kN; t += 64) {
        s += C[(size_t)t * kN + x[t]];
        s += Dall[m * kN + t] + Iall[m * kN + t];
    }
    #pragma unroll
    for (int off = 32; off > 0; off >>= 1) s += __shfl_down(s, off);
    if (lane == 0) loss_out[m] = s;
}

// ---- finalize -------------------------------------------------------------

__global__ void finalize(const float* __restrict__ loss_sums,
                         const float* __restrict__ score_w,
                         const float* __restrict__ score_b,
                         const float* __restrict__ avg_v,
                         float* __restrict__ out) {
    float mc[3];
    for (int m = 0; m < 3; ++m) mc[m] = 2.0f * (loss_sums[m] / (float)kNN) / (float)kNN;
    float logits = score_b[0];
    for (int m = 0; m < 3; ++m) logits += score_w[m] * mc[m];
    float score = 1.0f / (1.0f + expf(-logits));
    out[0] = score;
    out[1] = -logf(score) * avg_v[0];
    out[2] = mc[0];
    out[3] = mc[1];
    out[4] = mc[2];
}

// ---------------------------------------------------------------------------

extern "C" void kernel_launch(void* const* d_in, const int* in_sizes, int n_in,
                              void* d_out, int out_size, void* d_ws, size_t ws_size,
                              hipStream_t stream) {
    const int*   ei1 = (const int*)d_in[0];
    const int*   ei2 = (const int*)d_in[1];
    const float* x1  = (const float*)d_in[2];
    const float* x2  = (const float*)d_in[3];
    const float* avg = (const float*)d_in[6];

    const float *w[3], *b[3], *dl[3], *insp[3], *score_w, *score_b;
    if (in_sizes[11] == 8192) {  // dict order
        w[0]=(const float*)d_in[7];  b[0]=(const float*)d_in[8];
        dl[0]=(const float*)d_in[9]; insp[0]=(const float*)d_in[10];
        w[1]=(const float*)d_in[11]; b[1]=(const float*)d_in[12];
        dl[1]=(const float*)d_in[13]; insp[1]=(const float*)d_in[14];
        w[2]=(const float*)d_in[15]; b[2]=(const float*)d_in[16];
        dl[2]=(const float*)d_in[17]; insp[2]=(const float*)d_in[18];
        score_w=(const float*)d_in[19]; score_b=(const float*)d_in[20];
    } else {                     // signature order
        w[0]=(const float*)d_in[7];  b[0]=(const float*)d_in[8];
        w[1]=(const float*)d_in[9];  b[1]=(const float*)d_in[10];
        w[2]=(const float*)d_in[11]; b[2]=(const float*)d_in[12];
        dl[0]=(const float*)d_in[13]; dl[1]=(const float*)d_in[14]; dl[2]=(const float*)d_in[15];
        insp[0]=(const float*)d_in[16]; insp[1]=(const float*)d_in[17]; insp[2]=(const float*)d_in[18];
        score_w=(const float*)d_in[19]; score_b=(const float*)d_in[20];
    }

    // Workspace layout (float offsets)
    float* ws = (float*)d_ws;
    float* f1[3]  = { ws + 0,      ws + 49152,  ws + 73728  };  // 384x{128,64,32}
    float* f2[3]  = { ws + 86016,  ws + 135168, ws + 159744 };
    float* h      = ws + 172032;                                // 384x128 temp
    float* dinv1  = ws + 221184;
    float* dinv2  = ws + 221568;
    float* Dm     = ws + 221952;                                // 3 x 384
    float* Im     = ws + 223104;                                // 3 x 384
    unsigned* vbits = (unsigned*)(ws + 224256);                 // 3 x 384
    float* C      = ws + 225408;                                // 3 x 384 x 384
    float* loss   = ws + 667776;                                // 3

    init_deg<<<6, 64, 0, stream>>>(dinv1, dinv2);
    scatter_deg<<<24, 256, 0, stream>>>(ei1, ei2, dinv1, dinv2);
    deg_to_dinv<<<6, 64, 0, stream>>>(dinv1, dinv2);

    const int Fs[3] = {128, 64, 32};
    for (int g = 0; g < 2; ++g) {
        const float* xin  = g ? x2  : x1;
        const int*   ei   = g ? ei2 : ei1;
        float*       dinv = g ? dinv2 : dinv1;
        float* const* f   = g ? f2 : f1;
        int fin = 32, relu = 0;
        for (int li = 0; li < 3; ++li) {
            int OF = Fs[li];
            int nthr = kN * OF;
            gemm_act<<<(nthr + 255) / 256, 256, 0, stream>>>(xin, w[li], h, fin, OF, relu);
            agg_init<<<(nthr + 255) / 256, 256, 0, stream>>>(h, dinv, b[li], f[li], OF);
            agg_edges<<<(kE * OF + 255) / 256, 256, 0, stream>>>(ei, h, dinv, f[li], OF);
            xin = f[li]; fin = OF; relu = 1;
        }
    }

    hipMemsetAsync(vbits, 0, 3 * kN * sizeof(unsigned), stream);  // 0 == 0.0f bits

    for (int m = 0; m < 3; ++m) {
        node_dots<<<3, 128, 0, stream>>>(f1[m], dl[m],   Dm + m * kN, Fs[m]);
        node_dots<<<3, 128, 0, stream>>>(f2[m], insp[m], Im + m * kN, Fs[m]);
        build_cost_red<<<dim3(3, kN), 128, 0, stream>>>(f1[m], f2[m], Dm + m * kN,
                                                        Im + m * kN,
                                                        C + (size_t)m * kN * kN,
                                                        vbits + m * kN, Fs[m]);
    }

    lap384<<<3, 64, 0, stream>>>(C, vbits, Dm, Im, loss);
    finalize<<<1, 1, 0, stream>>>(loss, score_w, score_b, avg, (float*)d_out);
}

// Round 3
// 55738.599 us; speedup vs baseline: 6.4533x; 1.2438x over previous
//
#include <hip/hip_runtime.h>
#include <math.h>

// ---------------------------------------------------------------------------
// GOTSim: GCN features -> reduced 384x384 LAP (exact JV: col-reduction +
// greedy tight assign + augmenting row reduction + shortest augmenting path)
// LAP_768(block) = Sum(D)+Sum(I) + LAP_384(min(0, M_ij - D_i - I_j)).
// ---------------------------------------------------------------------------

namespace {
constexpr int kN   = 384;   // nodes per graph == reduced LAP dimension
constexpr int kNN  = 768;   // original LAP dimension (for normalization)
constexpr int kE   = 3072;  // edges per graph
constexpr float kInf = 1e30f;
}

// ---- wave64 reductions via DPP (row_shr 1,2,4,8 + row_bcast 15,31) --------

__device__ __forceinline__ float wave_min_bcast(float xv) {
    float v = xv;
    #define MSTAGE(ctrl) { int t = __builtin_amdgcn_update_dpp(__float_as_int(v), __float_as_int(v), ctrl, 0xF, 0xF, false); v = fminf(v, __int_as_float(t)); }
    MSTAGE(0x111); MSTAGE(0x112); MSTAGE(0x114); MSTAGE(0x118); MSTAGE(0x142); MSTAGE(0x143);
    #undef MSTAGE
    return __int_as_float(__builtin_amdgcn_readlane(__float_as_int(v), 63));
}

// joint (min, second-min) reduce; handles duplicate minima correctly
__device__ __forceinline__ void wave_min2_bcast(float m1, float m2, float& w1, float& w2) {
    #define M2STAGE(ctrl) { \
        int t1 = __builtin_amdgcn_update_dpp(__float_as_int(m1), __float_as_int(m1), ctrl, 0xF, 0xF, false); \
        int t2 = __builtin_amdgcn_update_dpp(__float_as_int(m2), __float_as_int(m2), ctrl, 0xF, 0xF, false); \
        float o1 = __int_as_float(t1); float o2 = __int_as_float(t2); \
        float n2 = fminf(fmaxf(m1, o1), fminf(m2, o2)); \
        m1 = fminf(m1, o1); m2 = n2; }
    M2STAGE(0x111); M2STAGE(0x112); M2STAGE(0x114); M2STAGE(0x118); M2STAGE(0x142); M2STAGE(0x143);
    #undef M2STAGE
    w1 = __int_as_float(__builtin_amdgcn_readlane(__float_as_int(m1), 63));
    w2 = __int_as_float(__builtin_amdgcn_readlane(__float_as_int(m2), 63));
}

// ---- degree / dinv --------------------------------------------------------

__global__ void init_deg(float* deg1, float* deg2) {
    int v = blockIdx.x * blockDim.x + threadIdx.x;
    if (v < kN) { deg1[v] = 1.0f; deg2[v] = 1.0f; }
}

__global__ void scatter_deg(const int* ei1, const int* ei2, float* deg1, float* deg2) {
    int e = blockIdx.x * blockDim.x + threadIdx.x;
    if (e < kE) {
        atomicAdd(&deg1[ei1[kE + e]], 1.0f);
    } else if (e < 2 * kE) {
        atomicAdd(&deg2[ei2[kE + (e - kE)]], 1.0f);
    }
}

__global__ void deg_to_dinv(float* deg1, float* deg2) {
    int v = blockIdx.x * blockDim.x + threadIdx.x;
    if (v < kN) { deg1[v] = rsqrtf(deg1[v]); deg2[v] = rsqrtf(deg2[v]); }
}

// ---- GCN layer ------------------------------------------------------------

__global__ void gemm_act(const float* __restrict__ x, const float* __restrict__ w,
                         float* __restrict__ h, int FIN, int FOUT, int relu) {
    int idx = blockIdx.x * blockDim.x + threadIdx.x;
    if (idx >= kN * FOUT) return;
    int row = idx / FOUT;
    int oc  = idx - row * FOUT;
    float acc = 0.0f;
    for (int k = 0; k < FIN; ++k) {
        float xv = x[row * FIN + k];
        if (relu) xv = fmaxf(xv, 0.0f);
        acc += xv * w[k * FOUT + oc];
    }
    h[idx] = acc;
}

__global__ void agg_init(const float* __restrict__ h, const float* __restrict__ dinv,
                         const float* __restrict__ b, float* __restrict__ out, int F) {
    int idx = blockIdx.x * blockDim.x + threadIdx.x;
    if (idx >= kN * F) return;
    int v = idx / F;
    int f = idx - v * F;
    float dv = dinv[v];
    out[idx] = b[f] + dv * dv * h[idx];
}

__global__ void agg_edges(const int* __restrict__ ei, const float* __restrict__ h,
                          const float* __restrict__ dinv, float* __restrict__ out, int F) {
    int idx = blockIdx.x * blockDim.x + threadIdx.x;
    if (idx >= kE * F) return;
    int e = idx / F;
    int f = idx - e * F;
    int s = ei[e];
    int d = ei[kE + e];
    atomicAdd(&out[d * F + f], dinv[s] * dinv[d] * h[s * F + f]);
}

// ---- diag terms -----------------------------------------------------------

__global__ void node_dots(const float* __restrict__ f, const float* __restrict__ p,
                          float* __restrict__ out, int F) {
    int i = blockIdx.x * blockDim.x + threadIdx.x;
    if (i >= kN) return;
    float acc = 0.0f;
    for (int k = 0; k < F; ++k) acc += f[i * F + k] * p[k];
    out[i] = -acc;
}

// ---- reduced cost matrix + column minima ----------------------------------
// Entries <= 0 so uint bits are order-reversed: atomicMax == float min.

__global__ void build_cost_red(const float* __restrict__ f1, const float* __restrict__ f2,
                               const float* __restrict__ D, const float* __restrict__ I,
                               float* __restrict__ C, unsigned* __restrict__ vbits, int F) {
    int j = blockIdx.x * blockDim.x + threadIdx.x;
    int i = blockIdx.y;
    if (j >= kN) return;
    float acc = 0.0f;
    for (int k = 0; k < F; ++k) acc += f1[i * F + k] * f2[j * F + k];
    float val = (-acc) - D[i] - I[j];
    float c = fminf(0.0f, val);
    C[i * kN + j] = c;
    atomicMax(&vbits[j], __float_as_uint(c));
}

// ---- 384x384 exact JV LAP, one wave per matrix ----------------------------

__global__ __launch_bounds__(64) void lap384(const float* __restrict__ Call,
                                             const unsigned* __restrict__ vbits_all,
                                             const float* __restrict__ Dall,
                                             const float* __restrict__ Iall,
                                             float* __restrict__ loss_out) {
    const int m = blockIdx.x;
    const float* C = Call + (size_t)m * kN * kN;
    const unsigned* vb = vbits_all + m * kN;
    const int lane = threadIdx.x;

    __shared__ float u[kN], v[kN];
    __shared__ int xr[kN], yc[kN];     // row->col, col->row
    __shared__ int2 sp[kN];            // (bits of shortest dist, pred row)
    __shared__ int2 step_ij[kN];       // (row scanned, col chosen)
    __shared__ int2 yu[kN];            // (yc[j], bits of u[yc[j]])
    __shared__ int freelist[kN];

    // --- init: v from column minima; clear assignment ---
    for (int j = lane; j < kN; j += 64) {
        v[j] = __uint_as_float(vb[j]);
        xr[j] = -1; yc[j] = -1;
        yu[j] = make_int2(-1, 0);
    }
    __syncthreads();

    // --- u_i = min_j (C_ij - v_j) ---
    {
        float umin[6];
        #pragma unroll
        for (int r = 0; r < 6; ++r) umin[r] = kInf;
        for (int j = 0; j < kN; ++j) {
            float vj = v[j];
            #pragma unroll
            for (int r = 0; r < 6; ++r)
                umin[r] = fminf(umin[r], C[(size_t)(lane + 64 * r) * kN + j] - vj);
        }
        #pragma unroll
        for (int r = 0; r < 6; ++r) u[lane + 64 * r] = umin[r];
    }
    __syncthreads();

    float vreg[6];
    #pragma unroll
    for (int r = 0; r < 6; ++r) vreg[r] = v[lane + 64 * r];

    // --- greedy tight assignment (free columns tracked in register mask) ---
    unsigned freemask = 0x3F;
    int nf = 0;
    for (int i = 0; i < kN; ++i) {
        float ui = u[i];
        const float* Crow = C + (size_t)i * kN;
        int cloc = 1 << 30;
        #pragma unroll
        for (int r = 0; r < 6; ++r) {
            int j = lane + 64 * r;
            if (((freemask >> r) & 1u) && (Crow[j] - vreg[r]) == ui && j < cloc) cloc = j;
        }
        unsigned long long mk = __ballot(cloc < (1 << 30));
        if (mk) {
            int src = __ffsll(mk) - 1;
            int cand = __builtin_amdgcn_readlane(cloc, src);
            if (lane == (cand & 63)) freemask &= ~(1u << (cand >> 6));
            if (lane == 0) {
                xr[i] = cand; yc[cand] = i;
                yu[cand] = make_int2(i, __float_as_int(ui));
            }
        } else {
            if (lane == 0) freelist[nf] = i;
            ++nf;
        }
    }

    // --- augmenting row reduction, 2 passes, op-capped ---
    int f0 = nf;
    bool capped = false;
    for (int pass = 0; pass < 2 && f0 > 0 && !capped; ++pass) {
        int k = 0, f = 0, ops = 0;
        int i = -1;
        for (;;) {
            if (i < 0) {
                if (k >= f0) break;
                i = freelist[k]; ++k;               // uniform LDS broadcast
            }
            if (++ops > 3 * kN) { capped = true; break; }
            const float* Crow = C + (size_t)i * kN;
            float m1 = kInf, m2 = kInf; int j1loc = 0, j2loc = 0;
            #pragma unroll
            for (int r = 0; r < 6; ++r) {
                int j = lane + 64 * r;
                float h = Crow[j] - vreg[r];
                if (h < m1) { m2 = m1; j2loc = j1loc; m1 = h; j1loc = j; }
                else if (h < m2) { m2 = h; j2loc = j; }
            }
            float w1, w2;
            wave_min2_bcast(m1, m2, w1, w2);
            unsigned long long mk = __ballot(m1 == w1);
            int l1 = __ffsll(mk) - 1;
            int j1 = __builtin_amdgcn_readlane(j1loc, l1);
            bool strict = (w1 < w2);
            int i0 = yc[j1];
            if (!strict && i0 >= 0) {               // tie & taken: use 2nd argmin col
                unsigned long long mk2 = mk & (mk - 1);
                int j2;
                if (mk2) j2 = __builtin_amdgcn_readlane(j1loc, __ffsll(mk2) - 1);
                else     j2 = __builtin_amdgcn_readlane(j2loc, l1);
                j1 = j2;
                i0 = yc[j1];
            }
            if (strict) {
                #pragma unroll
                for (int r = 0; r < 6; ++r)
                    if (lane == (j1 & 63) && r == (j1 >> 6)) {
                        vreg[r] -= (w2 - w1);
                        v[j1] = vreg[r];
                    }
            }
            if (lane == 0) {
                xr[i] = j1; yc[j1] = i; u[i] = w2;
                yu[j1] = make_int2(i, __float_as_int(w2));
            }
            if (i0 >= 0) {
                if (strict) { i = i0; }             // reprocess displaced row now
                else { if (lane == 0) freelist[f] = i0; ++f; i = -1; }
            } else i = -1;
        }
        if (capped) {
            if (i >= 0) { if (lane == 0) freelist[f] = i; ++f; }
            for (int t = k + lane; t < f0; t += 64) {  // f <= k: no overlap
                int val = freelist[t];
                freelist[f + (t - k)] = val;
            }
            f += (f0 - k);
        }
        f0 = f;
    }
    __syncthreads();

    // --- shortest augmenting path for remaining free rows ---
    const int nfree = f0;
    for (int fi = 0; fi < nfree; ++fi) {
        const int cur = freelist[fi];
        float sreg[6];
        unsigned scmask = 0;
        #pragma unroll
        for (int r = 0; r < 6; ++r) { sreg[r] = kInf; vreg[r] = v[lane + 64 * r]; }
        float min_val = 0.0f;
        float u_i = u[cur];
        int i = cur, sink = -1, nstep = 0;

        while (sink < 0) {
            float base = min_val - u_i;
            const float* Crow = C + (size_t)i * kN;
            float best = kInf; int bjloc = 0;
            #pragma unroll
            for (int r = 0; r < 6; ++r) {
                int j = lane + 64 * r;
                float c = Crow[j];
                float d = base + c - vreg[r];
                bool notsc = ((scmask >> r) & 1u) == 0u;
                if (notsc && d < sreg[r]) {
                    sreg[r] = d;
                    sp[j] = make_int2(__float_as_int(d), i);
                }
                float candv = notsc ? sreg[r] : kInf;
                if (candv < best) { best = candv; bjloc = j; }
            }
            float wmin = wave_min_bcast(best);
            unsigned long long mk = __ballot(best == wmin);
            int bj = __builtin_amdgcn_readlane(bjloc, __ffsll(mk) - 1);
            min_val = wmin;
            if (lane == (bj & 63)) scmask |= 1u << (bj >> 6);
            if (lane == 0) step_ij[nstep] = make_int2(i, bj);
            ++nstep;
            int2 p = yu[bj];                         // packed (y, u[y]) ds_read_b64
            if (p.x < 0) sink = bj;
            else { i = p.x; u_i = __int_as_float(p.y); }
        }

        __syncthreads();
        for (int t = lane; t < nstep; t += 64) {
            int2 sij = step_ij[t];
            int r = sij.x, jc = sij.y;
            v[jc] -= min_val - __int_as_float(sp[jc].x);
            if (r != cur) u[r] += min_val - __int_as_float(sp[xr[r]].x);
        }
        if (lane == 0) u[cur] += min_val;
        __syncthreads();
        if (lane == 0) {                             // augment along path
            int j = sink;
            for (;;) {
                int ii = sp[j].y;
                yc[j] = ii;
                int nxt = xr[ii];
                xr[ii] = j;
                j = nxt;
                if (ii == cur) break;
            }
        }
        __syncthreads();
        for (int t = lane; t < nstep; t += 64) {     // refresh yu for visited cols
            int jc = step_ij[t].y;
            int yy = yc[jc];
            yu[jc] = make_int2(yy, __float_as_int(u[yy]));
        }
        __syncthreads();
    }

    // --- loss = Sum D + Sum I + Sum_i C[i, x[i]] ---
    float s = 0.0f;
    for (int t = lane; t < kN; t += 64) {
        s += C[(size_t)t * kN + xr[t]];
        s += Dall[m * kN + t] + Iall[m * kN + t];
    }
    #pragma unroll
    for (int off = 32; off > 0; off >>= 1) s += __shfl_down(s, off);
    if (lane == 0) loss_out[m] = s;
}

// ---- finalize -------------------------------------------------------------

__global__ void finalize(const float* __restrict__ loss_sums,
                         const float* __restrict__ score_w,
                         const float* __restrict__ score_b,
                         const float* __restrict__ avg_v,
                         float* __restrict__ out) {
    float mc[3];
    for (int m = 0; m < 3; ++m) mc[m] = 2.0f * (loss_sums[m] / (float)kNN) / (float)kNN;
    float logits = score_b[0];
    for (int m = 0; m < 3; ++m) logits += score_w[m] * mc[m];
    float score = 1.0f / (1.0f + expf(-logits));
    out[0] = score;
    out[1] = -logf(score) * avg_v[0];
    out[2] = mc[0];
    out[3] = mc[1];
    out[4] = mc[2];
}

// ---------------------------------------------------------------------------

extern "C" void kernel_launch(void* const* d_in, const int* in_sizes, int n_in,
                              void* d_out, int out_size, void* d_ws, size_t ws_size,
                              hipStream_t stream) {
    const int*   ei1 = (const int*)d_in[0];
    const int*   ei2 = (const int*)d_in[1];
    const float* x1  = (const float*)d_in[2];
    const float* x2  = (const float*)d_in[3];
    const float* avg = (const float*)d_in[6];

    const float *w[3], *b[3], *dl[3], *insp[3], *score_w, *score_b;
    if (in_sizes[11] == 8192) {  // dict order
        w[0]=(const float*)d_in[7];  b[0]=(const float*)d_in[8];
        dl[0]=(const float*)d_in[9]; insp[0]=(const float*)d_in[10];
        w[1]=(const float*)d_in[11]; b[1]=(const float*)d_in[12];
        dl[1]=(const float*)d_in[13]; insp[1]=(const float*)d_in[14];
        w[2]=(const float*)d_in[15]; b[2]=(const float*)d_in[16];
        dl[2]=(const float*)d_in[17]; insp[2]=(const float*)d_in[18];
        score_w=(const float*)d_in[19]; score_b=(const float*)d_in[20];
    } else {                     // signature order
        w[0]=(const float*)d_in[7];  b[0]=(const float*)d_in[8];
        w[1]=(const float*)d_in[9];  b[1]=(const float*)d_in[10];
        w[2]=(const float*)d_in[11]; b[2]=(const float*)d_in[12];
        dl[0]=(const float*)d_in[13]; dl[1]=(const float*)d_in[14]; dl[2]=(const float*)d_in[15];
        insp[0]=(const float*)d_in[16]; insp[1]=(const float*)d_in[17]; insp[2]=(const float*)d_in[18];
        score_w=(const float*)d_in[19]; score_b=(const float*)d_in[20];
    }

    // Workspace layout (float offsets)
    float* ws = (float*)d_ws;
    float* f1[3]  = { ws + 0,      ws + 49152,  ws + 73728  };  // 384x{128,64,32}
    float* f2[3]  = { ws + 86016,  ws + 135168, ws + 159744 };
    float* h      = ws + 172032;                                // 384x128 temp
    float* dinv1  = ws + 221184;
    float* dinv2  = ws + 221568;
    float* Dm     = ws + 221952;                                // 3 x 384
    float* Im     = ws + 223104;                                // 3 x 384
    unsigned* vbits = (unsigned*)(ws + 224256);                 // 3 x 384
    float* C      = ws + 225408;                                // 3 x 384 x 384
    float* loss   = ws + 667776;                                // 3

    init_deg<<<6, 64, 0, stream>>>(dinv1, dinv2);
    scatter_deg<<<24, 256, 0, stream>>>(ei1, ei2, dinv1, dinv2);
    deg_to_dinv<<<6, 64, 0, stream>>>(dinv1, dinv2);

    const int Fs[3] = {128, 64, 32};
    for (int g = 0; g < 2; ++g) {
        const float* xin  = g ? x2  : x1;
        const int*   ei   = g ? ei2 : ei1;
        float*       dinv = g ? dinv2 : dinv1;
        float* const* f   = g ? f2 : f1;
        int fin = 32, relu = 0;
        for (int li = 0; li < 3; ++li) {
            int OF = Fs[li];
            int nthr = kN * OF;
            gemm_act<<<(nthr + 255) / 256, 256, 0, stream>>>(xin, w[li], h, fin, OF, relu);
            agg_init<<<(nthr + 255) / 256, 256, 0, stream>>>(h, dinv, b[li], f[li], OF);
            agg_edges<<<(kE * OF + 255) / 256, 256, 0, stream>>>(ei, h, dinv, f[li], OF);
            xin = f[li]; fin = OF; relu = 1;
        }
    }

    hipMemsetAsync(vbits, 0, 3 * kN * sizeof(unsigned), stream);  // 0 == bits of 0.0f

    for (int m = 0; m < 3; ++m) {
        node_dots<<<3, 128, 0, stream>>>(f1[m], dl[m],   Dm + m * kN, Fs[m]);
        node_dots<<<3, 128, 0, stream>>>(f2[m], insp[m], Im + m * kN, Fs[m]);
        build_cost_red<<<dim3(3, kN), 128, 0, stream>>>(f1[m], f2[m], Dm + m * kN,
                                                        Im + m * kN,
                                                        C + (size_t)m * kN * kN,
                                                        vbits + m * kN, Fs[m]);
    }

    lap384<<<3, 64, 0, stream>>>(C, vbits, Dm, Im, loss);
    finalize<<<1, 1, 0, stream>>>(loss, score_w, score_b, avg, (float*)d_out);
}

// Round 4
// 53705.286 us; speedup vs baseline: 6.6976x; 1.0379x over previous
//
#include <hip/hip_runtime.h>
#include <math.h>

// ---------------------------------------------------------------------------
// GOTSim: GCN features -> reduced 384x384 LAP (exact JV: col-reduction +
// fused greedy/u-init + augmenting row reduction + shortest augmenting path)
// LAP_768(block) = Sum(D)+Sum(I) + LAP_384(min(0, M_ij - D_i - I_j)).
// ---------------------------------------------------------------------------

namespace {
constexpr int kN   = 384;   // nodes per graph == reduced LAP dimension
constexpr int kNN  = 768;   // original LAP dimension (for normalization)
constexpr int kE   = 3072;  // edges per graph
constexpr float kInf = 1e30f;
}

// ---- wave64 reductions via DPP (row_shr 1,2,4,8 + row_bcast 15,31) --------
// Plain min: self-combine on DPP-disabled lanes is idempotent -> safe.
__device__ __forceinline__ float wave_min_bcast(float xv) {
    float v = xv;
    #define MSTAGE(ctrl) { int t = __builtin_amdgcn_update_dpp(__float_as_int(v), __float_as_int(v), ctrl, 0xF, 0xF, false); v = fminf(v, __int_as_float(t)); }
    MSTAGE(0x111); MSTAGE(0x112); MSTAGE(0x114); MSTAGE(0x118); MSTAGE(0x142); MSTAGE(0x143);
    #undef MSTAGE
    return __int_as_float(__builtin_amdgcn_readlane(__float_as_int(v), 63));
}

// (min, second-min): disabled lanes MUST contribute identity (+inf), else the
// pair self-combines and duplicates its min (w2 falsely == w1).  old = +inf.
__device__ __forceinline__ void wave_min2_bcast(float m1, float m2, float& w1, float& w2) {
    const int INFB = __float_as_int(kInf);
    #define M2STAGE(ctrl) { \
        int t1 = __builtin_amdgcn_update_dpp(INFB, __float_as_int(m1), ctrl, 0xF, 0xF, false); \
        int t2 = __builtin_amdgcn_update_dpp(INFB, __float_as_int(m2), ctrl, 0xF, 0xF, false); \
        float o1 = __int_as_float(t1); float o2 = __int_as_float(t2); \
        float n2 = fminf(fmaxf(m1, o1), fminf(m2, o2)); \
        m1 = fminf(m1, o1); m2 = n2; }
    M2STAGE(0x111); M2STAGE(0x112); M2STAGE(0x114); M2STAGE(0x118); M2STAGE(0x142); M2STAGE(0x143);
    #undef M2STAGE
    w1 = __int_as_float(__builtin_amdgcn_readlane(__float_as_int(m1), 63));
    w2 = __int_as_float(__builtin_amdgcn_readlane(__float_as_int(m2), 63));
}

// ---- degree / dinv --------------------------------------------------------

__global__ void init_deg(float* deg1, float* deg2) {
    int v = blockIdx.x * blockDim.x + threadIdx.x;
    if (v < kN) { deg1[v] = 1.0f; deg2[v] = 1.0f; }
}

__global__ void scatter_deg(const int* ei1, const int* ei2, float* deg1, float* deg2) {
    int e = blockIdx.x * blockDim.x + threadIdx.x;
    if (e < kE) {
        atomicAdd(&deg1[ei1[kE + e]], 1.0f);
    } else if (e < 2 * kE) {
        atomicAdd(&deg2[ei2[kE + (e - kE)]], 1.0f);
    }
}

__global__ void deg_to_dinv(float* deg1, float* deg2) {
    int v = blockIdx.x * blockDim.x + threadIdx.x;
    if (v < kN) { deg1[v] = rsqrtf(deg1[v]); deg2[v] = rsqrtf(deg2[v]); }
}

// ---- GCN layer ------------------------------------------------------------

__global__ void gemm_act(const float* __restrict__ x, const float* __restrict__ w,
                         float* __restrict__ h, int FIN, int FOUT, int relu) {
    int idx = blockIdx.x * blockDim.x + threadIdx.x;
    if (idx >= kN * FOUT) return;
    int row = idx / FOUT;
    int oc  = idx - row * FOUT;
    float acc = 0.0f;
    for (int k = 0; k < FIN; ++k) {
        float xv = x[row * FIN + k];
        if (relu) xv = fmaxf(xv, 0.0f);
        acc += xv * w[k * FOUT + oc];
    }
    h[idx] = acc;
}

__global__ void agg_init(const float* __restrict__ h, const float* __restrict__ dinv,
                         const float* __restrict__ b, float* __restrict__ out, int F) {
    int idx = blockIdx.x * blockDim.x + threadIdx.x;
    if (idx >= kN * F) return;
    int v = idx / F;
    int f = idx - v * F;
    float dv = dinv[v];
    out[idx] = b[f] + dv * dv * h[idx];
}

__global__ void agg_edges(const int* __restrict__ ei, const float* __restrict__ h,
                          const float* __restrict__ dinv, float* __restrict__ out, int F) {
    int idx = blockIdx.x * blockDim.x + threadIdx.x;
    if (idx >= kE * F) return;
    int e = idx / F;
    int f = idx - e * F;
    int s = ei[e];
    int d = ei[kE + e];
    atomicAdd(&out[d * F + f], dinv[s] * dinv[d] * h[s * F + f]);
}

// ---- diag terms -----------------------------------------------------------

__global__ void node_dots(const float* __restrict__ f, const float* __restrict__ p,
                          float* __restrict__ out, int F) {
    int i = blockIdx.x * blockDim.x + threadIdx.x;
    if (i >= kN) return;
    float acc = 0.0f;
    for (int k = 0; k < F; ++k) acc += f[i * F + k] * p[k];
    out[i] = -acc;
}

// ---- reduced cost matrix + column minima ----------------------------------
// Entries <= 0 so uint bits are order-reversed: atomicMax == float min.

__global__ void build_cost_red(const float* __restrict__ f1, const float* __restrict__ f2,
                               const float* __restrict__ D, const float* __restrict__ I,
                               float* __restrict__ C, unsigned* __restrict__ vbits, int F) {
    int j = blockIdx.x * blockDim.x + threadIdx.x;
    int i = blockIdx.y;
    if (j >= kN) return;
    float acc = 0.0f;
    for (int k = 0; k < F; ++k) acc += f1[i * F + k] * f2[j * F + k];
    float val = (-acc) - D[i] - I[j];
    float c = fminf(0.0f, val);
    C[i * kN + j] = c;
    atomicMax(&vbits[j], __float_as_uint(c));
}

// ---- 384x384 exact JV LAP, one wave per matrix ----------------------------

__global__ __launch_bounds__(64) void lap384(const float* __restrict__ Call,
                                             const unsigned* __restrict__ vbits_all,
                                             const float* __restrict__ Dall,
                                             const float* __restrict__ Iall,
                                             float* __restrict__ loss_out) {
    const int m = blockIdx.x;
    const float* C = Call + (size_t)m * kN * kN;
    const unsigned* vb = vbits_all + m * kN;
    const int lane = threadIdx.x;

    __shared__ float u[kN], v[kN];
    __shared__ int xr[kN], yc[kN];     // row->col, col->row
    __shared__ int2 sp[kN];            // (bits of shortest dist, pred row)
    __shared__ int2 step_ij[kN];       // (row scanned, col chosen)
    __shared__ int2 yu[kN];            // (yc[j], bits of u[yc[j]])
    __shared__ int flA[kN], flB[kN];   // ping-pong free-row lists

    // --- init: v from column minima; clear assignment ---
    for (int j = lane; j < kN; j += 64) {
        v[j] = __uint_as_float(vb[j]);
        xr[j] = -1; yc[j] = -1;
        yu[j] = make_int2(-1, 0);
    }
    __syncthreads();

    float vreg[6];
    #pragma unroll
    for (int r = 0; r < 6; ++r) vreg[r] = v[lane + 64 * r];

    // --- fused u-init + greedy tight assignment (row-major, coalesced) ---
    unsigned freemask = 0x3F;          // this lane's 6 columns free?
    int nf = 0;
    for (int i = 0; i < kN; ++i) {
        const float* Crow = C + (size_t)i * kN;
        float m1 = kInf; int j1loc = 0;
        #pragma unroll
        for (int r = 0; r < 6; ++r) {
            int j = lane + 64 * r;
            float hh = Crow[j] - vreg[r];
            if (hh < m1) { m1 = hh; j1loc = j; }
        }
        float w1 = wave_min_bcast(m1);
        int cloc = (m1 == w1 && ((freemask >> (j1loc >> 6)) & 1u)) ? j1loc : (1 << 30);
        unsigned long long mk = __ballot(cloc < (1 << 30));
        if (mk) {
            int cand = __builtin_amdgcn_readlane(cloc, __ffsll(mk) - 1);
            if (lane == (cand & 63)) freemask &= ~(1u << (cand >> 6));
            if (lane == 0) {
                xr[i] = cand; yc[cand] = i; u[i] = w1;
                yu[cand] = make_int2(i, __float_as_int(w1));
            }
        } else {
            if (lane == 0) { flA[nf] = i; u[i] = w1; }
            ++nf;
        }
    }

    // --- augmenting row reduction, 2 passes, tight-only, ping-pong lists ---
    int* src = flA; int* dst = flB;
    int f0 = nf;
    for (int pass = 0; pass < 2 && f0 > 0; ++pass) {
        int k = 0, f = 0, ops = 0;
        int i = -1;
        bool capped = false;
        for (;;) {
            if (i < 0) {
                if (k >= f0) break;
                i = src[k]; ++k;                     // uniform LDS broadcast
            }
            if (++ops > 4 * kN) {                    // churn guard
                if (lane == 0) dst[f] = i;
                ++f; capped = true; break;
            }
            const float* Crow = C + (size_t)i * kN;
            float m1 = kInf, m2 = kInf; int j1loc = 0;
            #pragma unroll
            for (int r = 0; r < 6; ++r) {
                int j = lane + 64 * r;
                float hh = Crow[j] - vreg[r];
                if (hh < m1) { m2 = m1; m1 = hh; j1loc = j; }
                else if (hh < m2) { m2 = hh; }
            }
            float w1, w2;
            wave_min2_bcast(m1, m2, w1, w2);
            unsigned long long mk = __ballot(m1 == w1);
            int j1 = __builtin_amdgcn_readlane(j1loc, __ffsll(mk) - 1);
            bool strict = (w1 < w2);
            int i0 = yc[j1];                         // uniform
            if (strict) {
                // lower v[j1] so (i,j1) is tight at u[i]=w2; chain-displace
                if (lane == (j1 & 63)) { vreg[j1 >> 6] -= (w2 - w1); v[j1] = vreg[j1 >> 6]; }
                if (lane == 0) {
                    xr[i] = j1; yc[j1] = i; u[i] = w2;
                    yu[j1] = make_int2(i, __float_as_int(w2));
                }
                i = (i0 >= 0) ? i0 : -1;
            } else {
                // tie at w1==w2: (i,j1) tight with u[i]=w1; owner -> next pass
                if (lane == 0) {
                    xr[i] = j1; yc[j1] = i; u[i] = w1;
                    yu[j1] = make_int2(i, __float_as_int(w1));
                }
                if (i0 >= 0) { if (lane == 0) dst[f] = i0; ++f; }
                i = -1;
            }
        }
        if (capped) {                                // append unprocessed tail
            for (int t = k + lane; t < f0; t += 64) dst[f + (t - k)] = src[t];
            f += f0 - k;
        }
        int* tmp = src; src = dst; dst = tmp;
        f0 = f;
    }
    __syncthreads();

    // --- shortest augmenting path for remaining free rows ---
    const int nfree = f0;
    for (int fi = 0; fi < nfree; ++fi) {
        const int cur = src[fi];
        float sreg[6];
        unsigned scmask = 0;
        #pragma unroll
        for (int r = 0; r < 6; ++r) { sreg[r] = kInf; vreg[r] = v[lane + 64 * r]; }
        float min_val = 0.0f;
        float u_i = u[cur];
        int i = cur, sink = -1, nstep = 0;

        while (sink < 0) {
            float base = min_val - u_i;
            const float* Crow = C + (size_t)i * kN;
            float best = kInf; int bjloc = 0;
            #pragma unroll
            for (int r = 0; r < 6; ++r) {
                int j = lane + 64 * r;
                float c = Crow[j];
                float d = base + c - vreg[r];
                bool notsc = ((scmask >> r) & 1u) == 0u;
                if (notsc && d < sreg[r]) {
                    sreg[r] = d;
                    sp[j] = make_int2(__float_as_int(d), i);
                }
                float candv = notsc ? sreg[r] : kInf;
                if (candv < best) { best = candv; bjloc = j; }
            }
            float wmin = wave_min_bcast(best);
            unsigned long long mk = __ballot(best == wmin);
            int bj = __builtin_amdgcn_readlane(bjloc, __ffsll(mk) - 1);
            min_val = wmin;
            if (lane == (bj & 63)) scmask |= 1u << (bj >> 6);
            if (lane == 0) step_ij[nstep] = make_int2(i, bj);
            ++nstep;
            int2 p = yu[bj];                         // packed (y, u[y])
            if (p.x < 0) sink = bj;
            else { i = p.x; u_i = __int_as_float(p.y); }
        }

        __syncthreads();
        for (int t = lane; t < nstep; t += 64) {
            int2 sij = step_ij[t];
            int r = sij.x, jc = sij.y;
            v[jc] -= min_val - __int_as_float(sp[jc].x);
            if (r != cur) u[r] += min_val - __int_as_float(sp[xr[r]].x);
        }
        if (lane == 0) u[cur] += min_val;
        __syncthreads();
        if (lane == 0) {                             // augment along path
            int j = sink;
            for (;;) {
                int ii = sp[j].y;
                yc[j] = ii;
                int nxt = xr[ii];
                xr[ii] = j;
                j = nxt;
                if (ii == cur) break;
            }
        }
        __syncthreads();
        for (int t = lane; t < nstep; t += 64) {     // refresh yu for SC cols
            int jc = step_ij[t].y;
            int yy = yc[jc];
            yu[jc] = make_int2(yy, __float_as_int(u[yy]));
        }
        __syncthreads();
    }

    // --- loss = Sum D + Sum I + Sum_i C[i, x[i]] ---
    float s = 0.0f;
    for (int t = lane; t < kN; t += 64) {
        s += C[(size_t)t * kN + xr[t]];
        s += Dall[m * kN + t] + Iall[m * kN + t];
    }
    #pragma unroll
    for (int off = 32; off > 0; off >>= 1) s += __shfl_down(s, off);
    if (lane == 0) loss_out[m] = s;
}

// ---- finalize -------------------------------------------------------------

__global__ void finalize(const float* __restrict__ loss_sums,
                         const float* __restrict__ score_w,
                         const float* __restrict__ score_b,
                         const float* __restrict__ avg_v,
                         float* __restrict__ out) {
    float mc[3];
    for (int m = 0; m < 3; ++m) mc[m] = 2.0f * (loss_sums[m] / (float)kNN) / (float)kNN;
    float logits = score_b[0];
    for (int m = 0; m < 3; ++m) logits += score_w[m] * mc[m];
    float score = 1.0f / (1.0f + expf(-logits));
    out[0] = score;
    out[1] = -logf(score) * avg_v[0];
    out[2] = mc[0];
    out[3] = mc[1];
    out[4] = mc[2];
}

// ---------------------------------------------------------------------------

extern "C" void kernel_launch(void* const* d_in, const int* in_sizes, int n_in,
                              void* d_out, int out_size, void* d_ws, size_t ws_size,
                              hipStream_t stream) {
    const int*   ei1 = (const int*)d_in[0];
    const int*   ei2 = (const int*)d_in[1];
    const float* x1  = (const float*)d_in[2];
    const float* x2  = (const float*)d_in[3];
    const float* avg = (const float*)d_in[6];

    const float *w[3], *b[3], *dl[3], *insp[3], *score_w, *score_b;
    if (in_sizes[11] == 8192) {  // dict order
        w[0]=(const float*)d_in[7];  b[0]=(const float*)d_in[8];
        dl[0]=(const float*)d_in[9]; insp[0]=(const float*)d_in[10];
        w[1]=(const float*)d_in[11]; b[1]=(const float*)d_in[12];
        dl[1]=(const float*)d_in[13]; insp[1]=(const float*)d_in[14];
        w[2]=(const float*)d_in[15]; b[2]=(const float*)d_in[16];
        dl[2]=(const float*)d_in[17]; insp[2]=(const float*)d_in[18];
        score_w=(const float*)d_in[19]; score_b=(const float*)d_in[20];
    } else {                     // signature order
        w[0]=(const float*)d_in[7];  b[0]=(const float*)d_in[8];
        w[1]=(const float*)d_in[9];  b[1]=(const float*)d_in[10];
        w[2]=(const float*)d_in[11]; b[2]=(const float*)d_in[12];
        dl[0]=(const float*)d_in[13]; dl[1]=(const float*)d_in[14]; dl[2]=(const float*)d_in[15];
        insp[0]=(const float*)d_in[16]; insp[1]=(const float*)d_in[17]; insp[2]=(const float*)d_in[18];
        score_w=(const float*)d_in[19]; score_b=(const float*)d_in[20];
    }

    // Workspace layout (float offsets)
    float* ws = (float*)d_ws;
    float* f1[3]  = { ws + 0,      ws + 49152,  ws + 73728  };  // 384x{128,64,32}
    float* f2[3]  = { ws + 86016,  ws + 135168, ws + 159744 };
    float* h      = ws + 172032;                                // 384x128 temp
    float* dinv1  = ws + 221184;
    float* dinv2  = ws + 221568;
    float* Dm     = ws + 221952;                                // 3 x 384
    float* Im     = ws + 223104;                                // 3 x 384
    unsigned* vbits = (unsigned*)(ws + 224256);                 // 3 x 384
    float* C      = ws + 225408;                                // 3 x 384 x 384
    float* loss   = ws + 667776;                                // 3

    init_deg<<<6, 64, 0, stream>>>(dinv1, dinv2);
    scatter_deg<<<24, 256, 0, stream>>>(ei1, ei2, dinv1, dinv2);
    deg_to_dinv<<<6, 64, 0, stream>>>(dinv1, dinv2);

    const int Fs[3] = {128, 64, 32};
    for (int g = 0; g < 2; ++g) {
        const float* xin  = g ? x2  : x1;
        const int*   ei   = g ? ei2 : ei1;
        float*       dinv = g ? dinv2 : dinv1;
        float* const* f   = g ? f2 : f1;
        int fin = 32, relu = 0;
        for (int li = 0; li < 3; ++li) {
            int OF = Fs[li];
            int nthr = kN * OF;
            gemm_act<<<(nthr + 255) / 256, 256, 0, stream>>>(xin, w[li], h, fin, OF, relu);
            agg_init<<<(nthr + 255) / 256, 256, 0, stream>>>(h, dinv, b[li], f[li], OF);
            agg_edges<<<(kE * OF + 255) / 256, 256, 0, stream>>>(ei, h, dinv, f[li], OF);
            xin = f[li]; fin = OF; relu = 1;
        }
    }

    hipMemsetAsync(vbits, 0, 3 * kN * sizeof(unsigned), stream);  // 0 == bits of +0.0f

    for (int m = 0; m < 3; ++m) {
        node_dots<<<3, 128, 0, stream>>>(f1[m], dl[m],   Dm + m * kN, Fs[m]);
        node_dots<<<3, 128, 0, stream>>>(f2[m], insp[m], Im + m * kN, Fs[m]);
        build_cost_red<<<dim3(3, kN), 128, 0, stream>>>(f1[m], f2[m], Dm + m * kN,
                                                        Im + m * kN,
                                                        C + (size_t)m * kN * kN,
                                                        vbits + m * kN, Fs[m]);
    }

    lap384<<<3, 64, 0, stream>>>(C, vbits, Dm, Im, loss);
    finalize<<<1, 1, 0, stream>>>(loss, score_w, score_b, avg, (float*)d_out);
}

// Round 5
// 53381.946 us; speedup vs baseline: 6.7382x; 1.0061x over previous
//
#include <hip/hip_runtime.h>
#include <math.h>

// ---------------------------------------------------------------------------
// GOTSim: GCN features -> reduced 384x384 LAP (exact JV: col-reduction +
// fused greedy/u-init + augmenting row reduction + FREE-COLUMN dual
// reduction + shortest augmenting path).
// LAP_768(block) = Sum(D)+Sum(I) + LAP_384(min(0, M_ij - D_i - I_j)).
// ---------------------------------------------------------------------------

namespace {
constexpr int kN   = 384;   // nodes per graph == reduced LAP dimension
constexpr int kNN  = 768;   // original LAP dimension (for normalization)
constexpr int kE   = 3072;  // edges per graph
constexpr float kInf = 1e30f;
}

// ---- wave64 reductions via DPP (row_shr 1,2,4,8 + row_bcast 15,31) --------
// Plain min: self-combine on DPP-disabled lanes is idempotent -> safe.
__device__ __forceinline__ float wave_min_bcast(float xv) {
    float v = xv;
    #define MSTAGE(ctrl) { int t = __builtin_amdgcn_update_dpp(__float_as_int(v), __float_as_int(v), ctrl, 0xF, 0xF, false); v = fminf(v, __int_as_float(t)); }
    MSTAGE(0x111); MSTAGE(0x112); MSTAGE(0x114); MSTAGE(0x118); MSTAGE(0x142); MSTAGE(0x143);
    #undef MSTAGE
    return __int_as_float(__builtin_amdgcn_readlane(__float_as_int(v), 63));
}

// (min, second-min): disabled lanes contribute identity (+inf) via old=INF.
__device__ __forceinline__ void wave_min2_bcast(float m1, float m2, float& w1, float& w2) {
    const int INFB = __float_as_int(kInf);
    #define M2STAGE(ctrl) { \
        int t1 = __builtin_amdgcn_update_dpp(INFB, __float_as_int(m1), ctrl, 0xF, 0xF, false); \
        int t2 = __builtin_amdgcn_update_dpp(INFB, __float_as_int(m2), ctrl, 0xF, 0xF, false); \
        float o1 = __int_as_float(t1); float o2 = __int_as_float(t2); \
        float n2 = fminf(fmaxf(m1, o1), fminf(m2, o2)); \
        m1 = fminf(m1, o1); m2 = n2; }
    M2STAGE(0x111); M2STAGE(0x112); M2STAGE(0x114); M2STAGE(0x118); M2STAGE(0x142); M2STAGE(0x143);
    #undef M2STAGE
    w1 = __int_as_float(__builtin_amdgcn_readlane(__float_as_int(m1), 63));
    w2 = __int_as_float(__builtin_amdgcn_readlane(__float_as_int(m2), 63));
}

// ---- degree / dinv --------------------------------------------------------

__global__ void init_deg(float* deg1, float* deg2) {
    int v = blockIdx.x * blockDim.x + threadIdx.x;
    if (v < kN) { deg1[v] = 1.0f; deg2[v] = 1.0f; }
}

__global__ void scatter_deg(const int* ei1, const int* ei2, float* deg1, float* deg2) {
    int e = blockIdx.x * blockDim.x + threadIdx.x;
    if (e < kE) {
        atomicAdd(&deg1[ei1[kE + e]], 1.0f);
    } else if (e < 2 * kE) {
        atomicAdd(&deg2[ei2[kE + (e - kE)]], 1.0f);
    }
}

__global__ void deg_to_dinv(float* deg1, float* deg2) {
    int v = blockIdx.x * blockDim.x + threadIdx.x;
    if (v < kN) { deg1[v] = rsqrtf(deg1[v]); deg2[v] = rsqrtf(deg2[v]); }
}

// ---- GCN layer ------------------------------------------------------------

__global__ void gemm_act(const float* __restrict__ x, const float* __restrict__ w,
                         float* __restrict__ h, int FIN, int FOUT, int relu) {
    int idx = blockIdx.x * blockDim.x + threadIdx.x;
    if (idx >= kN * FOUT) return;
    int row = idx / FOUT;
    int oc  = idx - row * FOUT;
    float acc = 0.0f;
    for (int k = 0; k < FIN; ++k) {
        float xv = x[row * FIN + k];
        if (relu) xv = fmaxf(xv, 0.0f);
        acc += xv * w[k * FOUT + oc];
    }
    h[idx] = acc;
}

__global__ void agg_init(const float* __restrict__ h, const float* __restrict__ dinv,
                         const float* __restrict__ b, float* __restrict__ out, int F) {
    int idx = blockIdx.x * blockDim.x + threadIdx.x;
    if (idx >= kN * F) return;
    int v = idx / F;
    int f = idx - v * F;
    float dv = dinv[v];
    out[idx] = b[f] + dv * dv * h[idx];
}

__global__ void agg_edges(const int* __restrict__ ei, const float* __restrict__ h,
                          const float* __restrict__ dinv, float* __restrict__ out, int F) {
    int idx = blockIdx.x * blockDim.x + threadIdx.x;
    if (idx >= kE * F) return;
    int e = idx / F;
    int f = idx - e * F;
    int s = ei[e];
    int d = ei[kE + e];
    atomicAdd(&out[d * F + f], dinv[s] * dinv[d] * h[s * F + f]);
}

// ---- diag terms -----------------------------------------------------------

__global__ void node_dots(const float* __restrict__ f, const float* __restrict__ p,
                          float* __restrict__ out, int F) {
    int i = blockIdx.x * blockDim.x + threadIdx.x;
    if (i >= kN) return;
    float acc = 0.0f;
    for (int k = 0; k < F; ++k) acc += f[i * F + k] * p[k];
    out[i] = -acc;
}

// ---- reduced cost matrix + column minima ----------------------------------
// Entries <= 0 so uint bits are order-reversed: atomicMax == float min.

__global__ void build_cost_red(const float* __restrict__ f1, const float* __restrict__ f2,
                               const float* __restrict__ D, const float* __restrict__ I,
                               float* __restrict__ C, unsigned* __restrict__ vbits, int F) {
    int j = blockIdx.x * blockDim.x + threadIdx.x;
    int i = blockIdx.y;
    if (j >= kN) return;
    float acc = 0.0f;
    for (int k = 0; k < F; ++k) acc += f1[i * F + k] * f2[j * F + k];
    float val = (-acc) - D[i] - I[j];
    float c = fminf(0.0f, val);
    C[i * kN + j] = c;
    atomicMax(&vbits[j], __float_as_uint(c));
}

// ---- 384x384 exact JV LAP, one wave per matrix ----------------------------

__global__ __launch_bounds__(64) void lap384(const float* __restrict__ Call,
                                             const unsigned* __restrict__ vbits_all,
                                             const float* __restrict__ Dall,
                                             const float* __restrict__ Iall,
                                             float* __restrict__ loss_out) {
    const int m = blockIdx.x;
    const float* C = Call + (size_t)m * kN * kN;
    const unsigned* vb = vbits_all + m * kN;
    const int lane = threadIdx.x;

    __shared__ float u[kN], v[kN];
    __shared__ int xr[kN], yc[kN];     // row->col, col->row
    __shared__ int2 sp[kN];            // (bits of shortest dist, pred row)
    __shared__ int2 step_ij[kN];       // (row scanned, col chosen)
    __shared__ int2 yu[kN];            // (yc[j], bits of u[yc[j]])
    __shared__ int flA[kN], flB[kN];   // ping-pong free-row lists
    __shared__ int fcl[kN];            // free-column list

    // --- init: v from column minima; clear assignment ---
    for (int j = lane; j < kN; j += 64) {
        v[j] = __uint_as_float(vb[j]);
        xr[j] = -1; yc[j] = -1;
        yu[j] = make_int2(-1, 0);
    }
    __syncthreads();

    float vreg[6];
    #pragma unroll
    for (int r = 0; r < 6; ++r) vreg[r] = v[lane + 64 * r];

    // --- fused u-init + greedy tight assignment (row-major, coalesced) ---
    unsigned freemask = 0x3F;          // this lane's 6 columns free?
    int nf = 0;
    for (int i = 0; i < kN; ++i) {
        const float* Crow = C + (size_t)i * kN;
        float m1 = kInf; int j1loc = 0;
        #pragma unroll
        for (int r = 0; r < 6; ++r) {
            int j = lane + 64 * r;
            float hh = Crow[j] - vreg[r];
            if (hh < m1) { m1 = hh; j1loc = j; }
        }
        float w1 = wave_min_bcast(m1);
        int cloc = (m1 == w1 && ((freemask >> (j1loc >> 6)) & 1u)) ? j1loc : (1 << 30);
        unsigned long long mk = __ballot(cloc < (1 << 30));
        if (mk) {
            int cand = __builtin_amdgcn_readlane(cloc, __ffsll(mk) - 1);
            if (lane == (cand & 63)) freemask &= ~(1u << (cand >> 6));
            if (lane == 0) {
                xr[i] = cand; yc[cand] = i; u[i] = w1;
                yu[cand] = make_int2(i, __float_as_int(w1));
            }
        } else {
            if (lane == 0) { flA[nf] = i; u[i] = w1; }
            ++nf;
        }
    }

    // --- augmenting row reduction, 2 passes, tight-only, ping-pong lists ---
    int* src = flA; int* dst = flB;
    int f0 = nf;
    for (int pass = 0; pass < 2 && f0 > 0; ++pass) {
        int k = 0, f = 0, ops = 0;
        int i = -1;
        bool capped = false;
        for (;;) {
            if (i < 0) {
                if (k >= f0) break;
                i = src[k]; ++k;                     // uniform LDS broadcast
            }
            if (++ops > 4 * kN) {                    // churn guard
                if (lane == 0) dst[f] = i;
                ++f; capped = true; break;
            }
            const float* Crow = C + (size_t)i * kN;
            float m1 = kInf, m2 = kInf; int j1loc = 0;
            #pragma unroll
            for (int r = 0; r < 6; ++r) {
                int j = lane + 64 * r;
                float hh = Crow[j] - vreg[r];
                if (hh < m1) { m2 = m1; m1 = hh; j1loc = j; }
                else if (hh < m2) { m2 = hh; }
            }
            float w1, w2;
            wave_min2_bcast(m1, m2, w1, w2);
            unsigned long long mk = __ballot(m1 == w1);
            int j1 = __builtin_amdgcn_readlane(j1loc, __ffsll(mk) - 1);
            bool strict = (w1 < w2);
            int i0 = yc[j1];                         // uniform
            if (strict) {
                // lower v[j1] so (i,j1) is tight at u[i]=w2; chain-displace
                if (lane == (j1 & 63)) { vreg[j1 >> 6] -= (w2 - w1); v[j1] = vreg[j1 >> 6]; }
                if (lane == 0) {
                    xr[i] = j1; yc[j1] = i; u[i] = w2;
                    yu[j1] = make_int2(i, __float_as_int(w2));
                }
                i = (i0 >= 0) ? i0 : -1;
            } else {
                // tie at w1==w2: (i,j1) tight with u[i]=w1; owner -> next pass
                if (lane == 0) {
                    xr[i] = j1; yc[j1] = i; u[i] = w1;
                    yu[j1] = make_int2(i, __float_as_int(w1));
                }
                if (i0 >= 0) { if (lane == 0) dst[f] = i0; ++f; }
                i = -1;
            }
        }
        if (capped) {                                // append unprocessed tail
            for (int t = k + lane; t < f0; t += 64) dst[f + (t - k)] = src[t];
            f += f0 - k;
        }
        int* tmp = src; src = dst; dst = tmp;
        f0 = f;
    }
    __syncthreads();

    // --- FREE-COLUMN dual reduction: v[j] = min_i (C[i][j] - u[i]) ---------
    // Makes every unmatched column tight (zero entry toll), so Dijkstra
    // finds free columns after ~n/nfree pops instead of flooding the whole
    // tight plateau (~n pops). Dual-feasible by construction.
    {
        int fc = 0;
        for (int base = 0; base < kN; base += 64) {
            int j = base + lane;
            bool isfree = (yc[j] < 0);
            unsigned long long mk = __ballot(isfree);
            int pos = fc + __popcll(mk & ((1ull << lane) - 1ull));
            if (isfree) fcl[pos] = j;
            fc += (int)__popcll(mk);
        }
        __syncthreads();
        for (int t = lane; t < fc; t += 64) {
            int j = fcl[t];
            float mn = kInf;
            #pragma unroll 4
            for (int i = 0; i < kN; ++i)
                mn = fminf(mn, C[(size_t)i * kN + j] - u[i]);
            v[j] = mn;
        }
        __syncthreads();
    }

    // --- shortest augmenting path for remaining free rows ---
    const int nfree = f0;
    for (int fi = 0; fi < nfree; ++fi) {
        const int cur = src[fi];
        float sreg[6];
        unsigned scmask = 0;
        #pragma unroll
        for (int r = 0; r < 6; ++r) { sreg[r] = kInf; vreg[r] = v[lane + 64 * r]; }
        float min_val = 0.0f;
        float u_i = u[cur];
        int i = cur, sink = -1, nstep = 0;

        while (sink < 0) {
            float base = min_val - u_i;
            const float* Crow = C + (size_t)i * kN;
            float best = kInf; int bjloc = 0;
            #pragma unroll
            for (int r = 0; r < 6; ++r) {
                int j = lane + 64 * r;
                float c = Crow[j];
                float d = base + c - vreg[r];
                bool notsc = ((scmask >> r) & 1u) == 0u;
                if (notsc && d < sreg[r]) {
                    sreg[r] = d;
                    sp[j] = make_int2(__float_as_int(d), i);
                }
                float candv = notsc ? sreg[r] : kInf;
                if (candv < best) { best = candv; bjloc = j; }
            }
            float wmin = wave_min_bcast(best);
            unsigned long long mk = __ballot(best == wmin);
            int bj = __builtin_amdgcn_readlane(bjloc, __ffsll(mk) - 1);
            min_val = wmin;
            if (lane == (bj & 63)) scmask |= 1u << (bj >> 6);
            if (lane == 0) step_ij[nstep] = make_int2(i, bj);
            ++nstep;
            int2 p = yu[bj];                         // packed (y, u[y])
            if (p.x < 0) sink = bj;
            else { i = p.x; u_i = __int_as_float(p.y); }
        }

        __syncthreads();
        for (int t = lane; t < nstep; t += 64) {
            int2 sij = step_ij[t];
            int r = sij.x, jc = sij.y;
            v[jc] -= min_val - __int_as_float(sp[jc].x);
            if (r != cur) u[r] += min_val - __int_as_float(sp[xr[r]].x);
        }
        if (lane == 0) u[cur] += min_val;
        __syncthreads();
        if (lane == 0) {                             // augment along path
            int j = sink;
            for (;;) {
                int ii = sp[j].y;
                yc[j] = ii;
                int nxt = xr[ii];
                xr[ii] = j;
                j = nxt;
                if (ii == cur) break;
            }
        }
        __syncthreads();
        for (int t = lane; t < nstep; t += 64) {     // refresh yu for SC cols
            int jc = step_ij[t].y;
            int yy = yc[jc];
            yu[jc] = make_int2(yy, __float_as_int(u[yy]));
        }
        __syncthreads();
    }

    // --- loss = Sum D + Sum I + Sum_i C[i, x[i]] ---
    float s = 0.0f;
    for (int t = lane; t < kN; t += 64) {
        s += C[(size_t)t * kN + xr[t]];
        s += Dall[m * kN + t] + Iall[m * kN + t];
    }
    #pragma unroll
    for (int off = 32; off > 0; off >>= 1) s += __shfl_down(s, off);
    if (lane == 0) loss_out[m] = s;
}

// ---- finalize -------------------------------------------------------------

__global__ void finalize(const float* __restrict__ loss_sums,
                         const float* __restrict__ score_w,
                         const float* __restrict__ score_b,
                         const float* __restrict__ avg_v,
                         float* __restrict__ out) {
    float mc[3];
    for (int m = 0; m < 3; ++m) mc[m] = 2.0f * (loss_sums[m] / (float)kNN) / (float)kNN;
    float logits = score_b[0];
    for (int m = 0; m < 3; ++m) logits += score_w[m] * mc[m];
    float score = 1.0f / (1.0f + expf(-logits));
    out[0] = score;
    out[1] = -logf(score) * avg_v[0];
    out[2] = mc[0];
    out[3] = mc[1];
    out[4] = mc[2];
}

// ---------------------------------------------------------------------------

extern "C" void kernel_launch(void* const* d_in, const int* in_sizes, int n_in,
                              void* d_out, int out_size, void* d_ws, size_t ws_size,
                              hipStream_t stream) {
    const int*   ei1 = (const int*)d_in[0];
    const int*   ei2 = (const int*)d_in[1];
    const float* x1  = (const float*)d_in[2];
    const float* x2  = (const float*)d_in[3];
    const float* avg = (const float*)d_in[6];

    const float *w[3], *b[3], *dl[3], *insp[3], *score_w, *score_b;
    if (in_sizes[11] == 8192) {  // dict order
        w[0]=(const float*)d_in[7];  b[0]=(const float*)d_in[8];
        dl[0]=(const float*)d_in[9]; insp[0]=(const float*)d_in[10];
        w[1]=(const float*)d_in[11]; b[1]=(const float*)d_in[12];
        dl[1]=(const float*)d_in[13]; insp[1]=(const float*)d_in[14];
        w[2]=(const float*)d_in[15]; b[2]=(const float*)d_in[16];
        dl[2]=(const float*)d_in[17]; insp[2]=(const float*)d_in[18];
        score_w=(const float*)d_in[19]; score_b=(const float*)d_in[20];
    } else {                     // signature order
        w[0]=(const float*)d_in[7];  b[0]=(const float*)d_in[8];
        w[1]=(const float*)d_in[9];  b[1]=(const float*)d_in[10];
        w[2]=(const float*)d_in[11]; b[2]=(const float*)d_in[12];
        dl[0]=(const float*)d_in[13]; dl[1]=(const float*)d_in[14]; dl[2]=(const float*)d_in[15];
        insp[0]=(const float*)d_in[16]; insp[1]=(const float*)d_in[17]; insp[2]=(const float*)d_in[18];
        score_w=(const float*)d_in[19]; score_b=(const float*)d_in[20];
    }

    // Workspace layout (float offsets)
    float* ws = (float*)d_ws;
    float* f1[3]  = { ws + 0,      ws + 49152,  ws + 73728  };  // 384x{128,64,32}
    float* f2[3]  = { ws + 86016,  ws + 135168, ws + 159744 };
    float* h      = ws + 172032;                                // 384x128 temp
    float* dinv1  = ws + 221184;
    float* dinv2  = ws + 221568;
    float* Dm     = ws + 221952;                                // 3 x 384
    float* Im     = ws + 223104;                                // 3 x 384
    unsigned* vbits = (unsigned*)(ws + 224256);                 // 3 x 384
    float* C      = ws + 225408;                                // 3 x 384 x 384
    float* loss   = ws + 667776;                                // 3

    init_deg<<<6, 64, 0, stream>>>(dinv1, dinv2);
    scatter_deg<<<24, 256, 0, stream>>>(ei1, ei2, dinv1, dinv2);
    deg_to_dinv<<<6, 64, 0, stream>>>(dinv1, dinv2);

    const int Fs[3] = {128, 64, 32};
    for (int g = 0; g < 2; ++g) {
        const float* xin  = g ? x2  : x1;
        const int*   ei   = g ? ei2 : ei1;
        float*       dinv = g ? dinv2 : dinv1;
        float* const* f   = g ? f2 : f1;
        int fin = 32, relu = 0;
        for (int li = 0; li < 3; ++li) {
            int OF = Fs[li];
            int nthr = kN * OF;
            gemm_act<<<(nthr + 255) / 256, 256, 0, stream>>>(xin, w[li], h, fin, OF, relu);
            agg_init<<<(nthr + 255) / 256, 256, 0, stream>>>(h, dinv, b[li], f[li], OF);
            agg_edges<<<(kE * OF + 255) / 256, 256, 0, stream>>>(ei, h, dinv, f[li], OF);
            xin = f[li]; fin = OF; relu = 1;
        }
    }

    hipMemsetAsync(vbits, 0, 3 * kN * sizeof(unsigned), stream);  // 0 == bits of +0.0f

    for (int m = 0; m < 3; ++m) {
        node_dots<<<3, 128, 0, stream>>>(f1[m], dl[m],   Dm + m * kN, Fs[m]);
        node_dots<<<3, 128, 0, stream>>>(f2[m], insp[m], Im + m * kN, Fs[m]);
        build_cost_red<<<dim3(3, kN), 128, 0, stream>>>(f1[m], f2[m], Dm + m * kN,
                                                        Im + m * kN,
                                                        C + (size_t)m * kN * kN,
                                                        vbits + m * kN, Fs[m]);
    }

    lap384<<<3, 64, 0, stream>>>(C, vbits, Dm, Im, loss);
    finalize<<<1, 1, 0, stream>>>(loss, score_w, score_b, avg, (float*)d_out);
}

// Round 7
// 32878.696 us; speedup vs baseline: 10.9401x; 1.6236x over previous
//
#include <hip/hip_runtime.h>
#include <math.h>

// ---------------------------------------------------------------------------
// GOTSim: GCN features -> reduced 384x384 LAP (exact JV: col-reduction +
// fused greedy/u-init + augmenting row reduction + free-column dual
// reduction + shortest augmenting path with BATCHED tie-popping).
// LAP_768(block) = Sum(D)+Sum(I) + LAP_384(min(0, M_ij - D_i - I_j)).
// ---------------------------------------------------------------------------

namespace {
constexpr int kN   = 384;   // nodes per graph == reduced LAP dimension
constexpr int kNN  = 768;   // original LAP dimension (for normalization)
constexpr int kE   = 3072;  // edges per graph
constexpr float kInf = 1e30f;
}

// ---- wave64 reductions via DPP (row_shr 1,2,4,8 + row_bcast 15,31) --------
// Plain min: self-combine on DPP-disabled lanes is idempotent -> safe.
__device__ __forceinline__ float wave_min_bcast(float xv) {
    float v = xv;
    #define MSTAGE(ctrl) { int t = __builtin_amdgcn_update_dpp(__float_as_int(v), __float_as_int(v), ctrl, 0xF, 0xF, false); v = fminf(v, __int_as_float(t)); }
    MSTAGE(0x111); MSTAGE(0x112); MSTAGE(0x114); MSTAGE(0x118); MSTAGE(0x142); MSTAGE(0x143);
    #undef MSTAGE
    return __int_as_float(__builtin_amdgcn_readlane(__float_as_int(v), 63));
}

// (min, second-min): disabled lanes contribute identity (+inf) via old=INF.
__device__ __forceinline__ void wave_min2_bcast(float m1, float m2, float& w1, float& w2) {
    const int INFB = __float_as_int(kInf);
    #define M2STAGE(ctrl) { \
        int t1 = __builtin_amdgcn_update_dpp(INFB, __float_as_int(m1), ctrl, 0xF, 0xF, false); \
        int t2 = __builtin_amdgcn_update_dpp(INFB, __float_as_int(m2), ctrl, 0xF, 0xF, false); \
        float o1 = __int_as_float(t1); float o2 = __int_as_float(t2); \
        float n2 = fminf(fmaxf(m1, o1), fminf(m2, o2)); \
        m1 = fminf(m1, o1); m2 = n2; }
    M2STAGE(0x111); M2STAGE(0x112); M2STAGE(0x114); M2STAGE(0x118); M2STAGE(0x142); M2STAGE(0x143);
    #undef M2STAGE
    w1 = __int_as_float(__builtin_amdgcn_readlane(__float_as_int(m1), 63));
    w2 = __int_as_float(__builtin_amdgcn_readlane(__float_as_int(m2), 63));
}

// ---- degree / dinv --------------------------------------------------------

__global__ void init_deg(float* deg1, float* deg2) {
    int v = blockIdx.x * blockDim.x + threadIdx.x;
    if (v < kN) { deg1[v] = 1.0f; deg2[v] = 1.0f; }
}

__global__ void scatter_deg(const int* ei1, const int* ei2, float* deg1, float* deg2) {
    int e = blockIdx.x * blockDim.x + threadIdx.x;
    if (e < kE) {
        atomicAdd(&deg1[ei1[kE + e]], 1.0f);
    } else if (e < 2 * kE) {
        atomicAdd(&deg2[ei2[kE + (e - kE)]], 1.0f);
    }
}

__global__ void deg_to_dinv(float* deg1, float* deg2) {
    int v = blockIdx.x * blockDim.x + threadIdx.x;
    if (v < kN) { deg1[v] = rsqrtf(deg1[v]); deg2[v] = rsqrtf(deg2[v]); }
}

// ---- GCN layer ------------------------------------------------------------

__global__ void gemm_act(const float* __restrict__ x, const float* __restrict__ w,
                         float* __restrict__ h, int FIN, int FOUT, int relu) {
    int idx = blockIdx.x * blockDim.x + threadIdx.x;
    if (idx >= kN * FOUT) return;
    int row = idx / FOUT;
    int oc  = idx - row * FOUT;
    float acc = 0.0f;
    for (int k = 0; k < FIN; ++k) {
        float xv = x[row * FIN + k];
        if (relu) xv = fmaxf(xv, 0.0f);
        acc += xv * w[k * FOUT + oc];
    }
    h[idx] = acc;
}

__global__ void agg_init(const float* __restrict__ h, const float* __restrict__ dinv,
                         const float* __restrict__ b, float* __restrict__ out, int F) {
    int idx = blockIdx.x * blockDim.x + threadIdx.x;
    if (idx >= kN * F) return;
    int v = idx / F;
    int f = idx - v * F;
    float dv = dinv[v];
    out[idx] = b[f] + dv * dv * h[idx];
}

__global__ void agg_edges(const int* __restrict__ ei, const float* __restrict__ h,
                          const float* __restrict__ dinv, float* __restrict__ out, int F) {
    int idx = blockIdx.x * blockDim.x + threadIdx.x;
    if (idx >= kE * F) return;
    int e = idx / F;
    int f = idx - e * F;
    int s = ei[e];
    int d = ei[kE + e];
    atomicAdd(&out[d * F + f], dinv[s] * dinv[d] * h[s * F + f]);
}

// ---- diag terms -----------------------------------------------------------

__global__ void node_dots(const float* __restrict__ f, const float* __restrict__ p,
                          float* __restrict__ out, int F) {
    int i = blockIdx.x * blockDim.x + threadIdx.x;
    if (i >= kN) return;
    float acc = 0.0f;
    for (int k = 0; k < F; ++k) acc += f[i * F + k] * p[k];
    out[i] = -acc;
}

// ---- reduced cost matrix + column minima ----------------------------------
// Entries <= 0 so uint bits are order-reversed: atomicMax == float min.

__global__ void build_cost_red(const float* __restrict__ f1, const float* __restrict__ f2,
                               const float* __restrict__ D, const float* __restrict__ I,
                               float* __restrict__ C, unsigned* __restrict__ vbits, int F) {
    int j = blockIdx.x * blockDim.x + threadIdx.x;
    int i = blockIdx.y;
    if (j >= kN) return;
    float acc = 0.0f;
    for (int k = 0; k < F; ++k) acc += f1[i * F + k] * f2[j * F + k];
    float val = (-acc) - D[i] - I[j];
    float c = fminf(0.0f, val);
    C[i * kN + j] = c;
    atomicMax(&vbits[j], __float_as_uint(c));
}

// ---- 384x384 exact JV LAP, one wave per matrix ----------------------------

__global__ __launch_bounds__(64) void lap384(const float* __restrict__ Call,
                                             const unsigned* __restrict__ vbits_all,
                                             const float* __restrict__ Dall,
                                             const float* __restrict__ Iall,
                                             float* __restrict__ loss_out) {
    const int m = blockIdx.x;
    const float* C = Call + (size_t)m * kN * kN;
    const unsigned* vb = vbits_all + m * kN;
    const int lane = threadIdx.x;

    __shared__ float u[kN], v[kN];
    __shared__ int xr[kN], yc[kN];     // row->col, col->row
    __shared__ int2 sp[kN];            // (bits of shortest dist, pred row)
    __shared__ int2 steps[kN];         // (pre-augment matched row of col, col)
    __shared__ int2 yu[kN];            // (yc[j], bits of u[yc[j]])
    __shared__ int2 rbatch[kN];        // rows to relax this iteration
    __shared__ int flA[kN], flB[kN];   // ping-pong free-row lists
    __shared__ int fcl[kN];            // free-column list

    // --- init: v from column minima; clear assignment ---
    for (int j = lane; j < kN; j += 64) {
        v[j] = __uint_as_float(vb[j]);
        xr[j] = -1; yc[j] = -1;
        yu[j] = make_int2(-1, 0);
    }
    __syncthreads();

    float vreg[6];
    #pragma unroll
    for (int r = 0; r < 6; ++r) vreg[r] = v[lane + 64 * r];

    // --- fused u-init + greedy tight assignment (row-major, coalesced) ---
    unsigned freemask = 0x3F;          // this lane's 6 columns free?
    int nf = 0;
    for (int i = 0; i < kN; ++i) {
        const float* Crow = C + (size_t)i * kN;
        float m1 = kInf; int j1loc = 0;
        #pragma unroll
        for (int r = 0; r < 6; ++r) {
            int j = lane + 64 * r;
            float hh = Crow[j] - vreg[r];
            if (hh < m1) { m1 = hh; j1loc = j; }
        }
        float w1 = wave_min_bcast(m1);
        int cloc = (m1 == w1 && ((freemask >> (j1loc >> 6)) & 1u)) ? j1loc : (1 << 30);
        unsigned long long mk = __ballot(cloc < (1 << 30));
        if (mk) {
            int cand = __builtin_amdgcn_readlane(cloc, __ffsll(mk) - 1);
            if (lane == (cand & 63)) freemask &= ~(1u << (cand >> 6));
            if (lane == 0) {
                xr[i] = cand; yc[cand] = i; u[i] = w1;
                yu[cand] = make_int2(i, __float_as_int(w1));
            }
        } else {
            if (lane == 0) { flA[nf] = i; u[i] = w1; }
            ++nf;
        }
    }

    // --- augmenting row reduction, 2 passes, tight-only, ping-pong lists ---
    int* src = flA; int* dst = flB;
    int f0 = nf;
    for (int pass = 0; pass < 2 && f0 > 0; ++pass) {
        int k = 0, f = 0, ops = 0;
        int i = -1;
        bool capped = false;
        for (;;) {
            if (i < 0) {
                if (k >= f0) break;
                i = src[k]; ++k;                     // uniform LDS broadcast
            }
            if (++ops > 4 * kN) {                    // churn guard
                if (lane == 0) dst[f] = i;
                ++f; capped = true; break;
            }
            const float* Crow = C + (size_t)i * kN;
            float m1 = kInf, m2 = kInf; int j1loc = 0;
            #pragma unroll
            for (int r = 0; r < 6; ++r) {
                int j = lane + 64 * r;
                float hh = Crow[j] - vreg[r];
                if (hh < m1) { m2 = m1; m1 = hh; j1loc = j; }
                else if (hh < m2) { m2 = hh; }
            }
            float w1, w2;
            wave_min2_bcast(m1, m2, w1, w2);
            unsigned long long mk = __ballot(m1 == w1);
            int j1 = __builtin_amdgcn_readlane(j1loc, __ffsll(mk) - 1);
            bool strict = (w1 < w2);
            int i0 = yc[j1];                         // uniform
            if (strict) {
                // lower v[j1] so (i,j1) is tight at u[i]=w2; chain-displace
                if (lane == (j1 & 63)) { vreg[j1 >> 6] -= (w2 - w1); v[j1] = vreg[j1 >> 6]; }
                if (lane == 0) {
                    xr[i] = j1; yc[j1] = i; u[i] = w2;
                    yu[j1] = make_int2(i, __float_as_int(w2));
                }
                i = (i0 >= 0) ? i0 : -1;
            } else {
                // tie at w1==w2: (i,j1) tight with u[i]=w1; owner -> next pass
                if (lane == 0) {
                    xr[i] = j1; yc[j1] = i; u[i] = w1;
                    yu[j1] = make_int2(i, __float_as_int(w1));
                }
                if (i0 >= 0) { if (lane == 0) dst[f] = i0; ++f; }
                i = -1;
            }
        }
        if (capped) {                                // append unprocessed tail
            for (int t = k + lane; t < f0; t += 64) dst[f + (t - k)] = src[t];
            f += f0 - k;
        }
        int* tmp = src; src = dst; dst = tmp;
        f0 = f;
    }
    __syncthreads();

    // --- free-column dual reduction: v[j] = min_i (C[i][j] - u[i]) ---------
    {
        int fc = 0;
        for (int base = 0; base < kN; base += 64) {
            int j = base + lane;
            bool isfree = (yc[j] < 0);
            unsigned long long mk = __ballot(isfree);
            int pos = fc + __popcll(mk & ((1ull << lane) - 1ull));
            if (isfree) fcl[pos] = j;
            fc += (int)__popcll(mk);
        }
        __syncthreads();
        for (int t = lane; t < fc; t += 64) {
            int j = fcl[t];
            float mn = kInf;
            #pragma unroll 4
            for (int i = 0; i < kN; ++i)
                mn = fminf(mn, C[(size_t)i * kN + j] - u[i]);
            v[j] = mn;
        }
        __syncthreads();
    }

    // --- shortest augmenting path w/ batched tie-popping -------------------
    // SC exclusion via per-lane 6-bit scmask: popped columns are never
    // re-relaxed (matched edges are tight -> would instantly re-pop: hang).
    const int nfree = f0;
    for (int fi = 0; fi < nfree; ++fi) {
        const int cur = src[fi];
        float sreg[6];
        unsigned scmask = 0;
        #pragma unroll
        for (int r = 0; r < 6; ++r) { sreg[r] = kInf; vreg[r] = v[lane + 64 * r]; }
        float min_val = 0.0f;
        int sink = -1;
        int scount = 0;
        int nbatch = 1;
        int iters = 0;
        if (lane == 0) rbatch[0] = make_int2(cur, __float_as_int(u[cur]));
        __syncthreads();

        while (true) {
            // relax all rows in rbatch, chunks of 4 (padded with last entry)
            for (int t0 = 0; t0 < nbatch; t0 += 4) {
                int2 e0 = rbatch[t0];
                int2 e1 = rbatch[(t0 + 1 < nbatch) ? t0 + 1 : nbatch - 1];
                int2 e2 = rbatch[(t0 + 2 < nbatch) ? t0 + 2 : nbatch - 1];
                int2 e3 = rbatch[(t0 + 3 < nbatch) ? t0 + 3 : nbatch - 1];
                float b0 = min_val - __int_as_float(e0.y);
                float b1 = min_val - __int_as_float(e1.y);
                float b2 = min_val - __int_as_float(e2.y);
                float b3 = min_val - __int_as_float(e3.y);
                const float* R0 = C + (size_t)e0.x * kN;
                const float* R1 = C + (size_t)e1.x * kN;
                const float* R2 = C + (size_t)e2.x * kN;
                const float* R3 = C + (size_t)e3.x * kN;
                float c0[6], c1[6], c2[6], c3[6];
                #pragma unroll
                for (int r = 0; r < 6; ++r) {
                    int j = lane + 64 * r;
                    c0[r] = R0[j]; c1[r] = R1[j]; c2[r] = R2[j]; c3[r] = R3[j];
                }
                #pragma unroll
                for (int r = 0; r < 6; ++r) {
                    int j = lane + 64 * r;
                    float db = sreg[r]; int pred = -1;
                    float d0 = b0 + c0[r] - vreg[r];
                    if (d0 < db) { db = d0; pred = e0.x; }
                    float d1 = b1 + c1[r] - vreg[r];
                    if (d1 < db) { db = d1; pred = e1.x; }
                    float d2 = b2 + c2[r] - vreg[r];
                    if (d2 < db) { db = d2; pred = e2.x; }
                    float d3 = b3 + c3[r] - vreg[r];
                    if (d3 < db) { db = d3; pred = e3.x; }
                    bool notsc = ((scmask >> r) & 1u) == 0u;
                    if (notsc && pred >= 0) {
                        sreg[r] = db;
                        sp[j] = make_int2(__float_as_int(db), pred);
                    }
                }
            }

            // global min over remaining (non-popped) columns
            float best = fminf(fminf(fminf(sreg[0], sreg[1]), fminf(sreg[2], sreg[3])),
                               fminf(sreg[4], sreg[5]));
            min_val = wave_min_bcast(best);

            // pop ALL columns at min_val (Dijkstra finalizes all ties at once)
            nbatch = 0;
            #pragma unroll
            for (int r = 0; r < 6; ++r) {
                bool notsc = ((scmask >> r) & 1u) == 0u;
                bool elig = notsc && (sreg[r] == min_val);
                unsigned long long mk = __ballot(elig);
                if (mk == 0) continue;
                int j = lane + 64 * r;
                int2 p = make_int2(0, 0);
                if (elig) { p = yu[j]; sreg[r] = kInf; scmask |= 1u << r; }
                int pos = (int)__popcll(mk & ((1ull << lane) - 1ull));
                if (elig) {
                    steps[scount + pos] = make_int2(p.x, j);
                    rbatch[nbatch + pos] = p;
                }
                int cnt = (int)__popcll(mk);
                unsigned long long fmk = __ballot(elig && p.x < 0);
                if (fmk != 0 && sink < 0) sink = (__ffsll(fmk) - 1) + 64 * r;
                scount += cnt; nbatch += cnt;
            }
            if (sink >= 0) break;
            if (++iters > kN + 1) break;             // safety; never in practice
            __syncthreads();   // order LDS rbatch writes before next relax
        }

        __syncthreads();
        if (sink >= 0) {
            // dual updates: per popped column jc (matched row i pre-augment):
            //   v[jc] -= min_val - d_jc ;  u[i] += min_val - d_jc
            for (int t = lane; t < scount; t += 64) {
                int2 sij = steps[t];
                int i = sij.x, jc = sij.y;
                float adj = min_val - __int_as_float(sp[jc].x);
                v[jc] -= adj;
                if (i >= 0) u[i] += adj;
            }
            if (lane == 0) u[cur] += min_val;
            __syncthreads();
            if (lane == 0) {                         // augment along path
                int j = sink;
                for (;;) {
                    int ii = sp[j].y;
                    yc[j] = ii;
                    int nxt = xr[ii];
                    xr[ii] = j;
                    j = nxt;
                    if (ii == cur) break;
                }
            }
            __syncthreads();
            for (int t = lane; t < scount; t += 64) { // refresh yu for SC cols
                int jc = steps[t].y;
                int yy = yc[jc];
                yu[jc] = make_int2(yy, (yy >= 0) ? __float_as_int(u[yy]) : 0);
            }
            __syncthreads();
        }
    }

    // --- loss = Sum D + Sum I + Sum_i C[i, x[i]] ---
    float s = 0.0f;
    for (int t = lane; t < kN; t += 64) {
        s += C[(size_t)t * kN + xr[t]];
        s += Dall[m * kN + t] + Iall[m * kN + t];
    }
    #pragma unroll
    for (int off = 32; off > 0; off >>= 1) s += __shfl_down(s, off);
    if (lane == 0) loss_out[m] = s;
}

// ---- finalize -------------------------------------------------------------

__global__ void finalize(const float* __restrict__ loss_sums,
                         const float* __restrict__ score_w,
                         const float* __restrict__ score_b,
                         const float* __restrict__ avg_v,
                         float* __restrict__ out) {
    float mc[3];
    for (int m = 0; m < 3; ++m) mc[m] = 2.0f * (loss_sums[m] / (float)kNN) / (float)kNN;
    float logits = score_b[0];
    for (int m = 0; m < 3; ++m) logits += score_w[m] * mc[m];
    float score = 1.0f / (1.0f + expf(-logits));
    out[0] = score;
    out[1] = -logf(score) * avg_v[0];
    out[2] = mc[0];
    out[3] = mc[1];
    out[4] = mc[2];
}

// ---------------------------------------------------------------------------

extern "C" void kernel_launch(void* const* d_in, const int* in_sizes, int n_in,
                              void* d_out, int out_size, void* d_ws, size_t ws_size,
                              hipStream_t stream) {
    const int*   ei1 = (const int*)d_in[0];
    const int*   ei2 = (const int*)d_in[1];
    const float* x1  = (const float*)d_in[2];
    const float* x2  = (const float*)d_in[3];
    const float* avg = (const float*)d_in[6];

    const float *w[3], *b[3], *dl[3], *insp[3], *score_w, *score_b;
    if (in_sizes[11] == 8192) {  // dict order
        w[0]=(const float*)d_in[7];  b[0]=(const float*)d_in[8];
        dl[0]=(const float*)d_in[9]; insp[0]=(const float*)d_in[10];
        w[1]=(const float*)d_in[11]; b[1]=(const float*)d_in[12];
        dl[1]=(const float*)d_in[13]; insp[1]=(const float*)d_in[14];
        w[2]=(const float*)d_in[15]; b[2]=(const float*)d_in[16];
        dl[2]=(const float*)d_in[17]; insp[2]=(const float*)d_in[18];
        score_w=(const float*)d_in[19]; score_b=(const float*)d_in[20];
    } else {                     // signature order
        w[0]=(const float*)d_in[7];  b[0]=(const float*)d_in[8];
        w[1]=(const float*)d_in[9];  b[1]=(const float*)d_in[10];
        w[2]=(const float*)d_in[11]; b[2]=(const float*)d_in[12];
        dl[0]=(const float*)d_in[13]; dl[1]=(const float*)d_in[14]; dl[2]=(const float*)d_in[15];
        insp[0]=(const float*)d_in[16]; insp[1]=(const float*)d_in[17]; insp[2]=(const float*)d_in[18];
        score_w=(const float*)d_in[19]; score_b=(const float*)d_in[20];
    }

    // Workspace layout (float offsets)
    float* ws = (float*)d_ws;
    float* f1[3]  = { ws + 0,      ws + 49152,  ws + 73728  };  // 384x{128,64,32}
    float* f2[3]  = { ws + 86016,  ws + 135168, ws + 159744 };
    float* h      = ws + 172032;                                // 384x128 temp
    float* dinv1  = ws + 221184;
    float* dinv2  = ws + 221568;
    float* Dm     = ws + 221952;                                // 3 x 384
    float* Im     = ws + 223104;                                // 3 x 384
    unsigned* vbits = (unsigned*)(ws + 224256);                 // 3 x 384
    float* C      = ws + 225408;                                // 3 x 384 x 384
    float* loss   = ws + 667776;                                // 3

    init_deg<<<6, 64, 0, stream>>>(dinv1, dinv2);
    scatter_deg<<<24, 256, 0, stream>>>(ei1, ei2, dinv1, dinv2);
    deg_to_dinv<<<6, 64, 0, stream>>>(dinv1, dinv2);

    const int Fs[3] = {128, 64, 32};
    for (int g = 0; g < 2; ++g) {
        const float* xin  = g ? x2  : x1;
        const int*   ei   = g ? ei2 : ei1;
        float*       dinv = g ? dinv2 : dinv1;
        float* const* f   = g ? f2 : f1;
        int fin = 32, relu = 0;
        for (int li = 0; li < 3; ++li) {
            int OF = Fs[li];
            int nthr = kN * OF;
            gemm_act<<<(nthr + 255) / 256, 256, 0, stream>>>(xin, w[li], h, fin, OF, relu);
            agg_init<<<(nthr + 255) / 256, 256, 0, stream>>>(h, dinv, b[li], f[li], OF);
            agg_edges<<<(kE * OF + 255) / 256, 256, 0, stream>>>(ei, h, dinv, f[li], OF);
            xin = f[li]; fin = OF; relu = 1;
        }
    }

    hipMemsetAsync(vbits, 0, 3 * kN * sizeof(unsigned), stream);  // 0 == bits of +0.0f

    for (int m = 0; m < 3; ++m) {
        node_dots<<<3, 128, 0, stream>>>(f1[m], dl[m],   Dm + m * kN, Fs[m]);
        node_dots<<<3, 128, 0, stream>>>(f2[m], insp[m], Im + m * kN, Fs[m]);
        build_cost_red<<<dim3(3, kN), 128, 0, stream>>>(f1[m], f2[m], Dm + m * kN,
                                                        Im + m * kN,
                                                        C + (size_t)m * kN * kN,
                                                        vbits + m * kN, Fs[m]);
    }

    lap384<<<3, 64, 0, stream>>>(C, vbits, Dm, Im, loss);
    finalize<<<1, 1, 0, stream>>>(loss, score_w, score_b, avg, (float*)d_out);
}